// Round 1
// baseline (1430.673 us; speedup 1.0000x reference)
//
#include <hip/hip_runtime.h>
#include <math.h>

#define D_STATE 16
#define D_CONV 4
#define DT_RANK 64
#define D_INNER 2048
#define D_MODEL 1024
#define BATCH 2
#define SEQLEN 1024
#define M_TOTAL (BATCH*SEQLEN)  // 2048

__device__ __forceinline__ float silu_f(float x) {
    return x / (1.0f + __expf(-x));
}
__device__ __forceinline__ float softplus_f(float x) {
    // jax.nn.softplus = logaddexp(x, 0) = max(x,0) + log1p(exp(-|x|))
    return fmaxf(x, 0.0f) + log1pf(__expf(-fabsf(x)));
}

// ---------------------------------------------------------------------------
// Generic NT GEMM: C[m,n] = sum_k A[m*lda+k] * B[n*ldb+k]   (both K-contiguous)
// MODE 0: v=acc+bias[n]; n<D_INNER -> out0[m*D_INNER+n]=v else out1[...]=silu(v)
// MODE 1: out0[m*N+n] = acc
// MODE 2: out0[m*N+n] = softplus(acc + bias[n])
// MODE 3: out0[m*N+n] = acc + bias[n]
// ---------------------------------------------------------------------------
template<int BM, int BN, int BK, int TM, int TN, int MODE>
__global__ __launch_bounds__((BM/TM)*(BN/TN))
void gemm_nt(const float* __restrict__ A, int lda,
             const float* __restrict__ B, int ldb,
             const float* __restrict__ bias,
             float* __restrict__ out0, float* __restrict__ out1,
             int M, int N, int K)
{
    constexpr int THREADS = (BM/TM)*(BN/TN);
    __shared__ float As[BK][BM+4];
    __shared__ float Bs[BK][BN+4];
    const int tid = threadIdx.x;
    const int bm = blockIdx.y * BM;
    const int bn = blockIdx.x * BN;
    const int tx = tid % (BN/TN);   // n-direction
    const int ty = tid / (BN/TN);   // m-direction

    float acc[TM][TN];
    #pragma unroll
    for (int i = 0; i < TM; i++)
        #pragma unroll
        for (int j = 0; j < TN; j++) acc[i][j] = 0.0f;

    constexpr int F4_PER_ROW = BK / 4;             // float4 chunks per K-row
    constexpr int A_ROWS_PER_ITER = THREADS / F4_PER_ROW;
    constexpr int B_ROWS_PER_ITER = THREADS / F4_PER_ROW;

    for (int kt = 0; kt < K; kt += BK) {
        #pragma unroll
        for (int r = 0; r < BM; r += A_ROWS_PER_ITER) {
            int row = r + tid / F4_PER_ROW;
            int kc  = (tid % F4_PER_ROW) * 4;
            float4 v = *(const float4*)(A + (size_t)(bm + row) * lda + kt + kc);
            As[kc+0][row] = v.x; As[kc+1][row] = v.y;
            As[kc+2][row] = v.z; As[kc+3][row] = v.w;
        }
        #pragma unroll
        for (int r = 0; r < BN; r += B_ROWS_PER_ITER) {
            int row = r + tid / F4_PER_ROW;
            int kc  = (tid % F4_PER_ROW) * 4;
            float4 v = *(const float4*)(B + (size_t)(bn + row) * ldb + kt + kc);
            Bs[kc+0][row] = v.x; Bs[kc+1][row] = v.y;
            Bs[kc+2][row] = v.z; Bs[kc+3][row] = v.w;
        }
        __syncthreads();
        #pragma unroll
        for (int k = 0; k < BK; k++) {
            float ra[TM], rb[TN];
            #pragma unroll
            for (int i = 0; i < TM; i++) ra[i] = As[k][ty*TM + i];
            #pragma unroll
            for (int j = 0; j < TN; j++) rb[j] = Bs[k][tx*TN + j];
            #pragma unroll
            for (int i = 0; i < TM; i++)
                #pragma unroll
                for (int j = 0; j < TN; j++) acc[i][j] += ra[i] * rb[j];
        }
        __syncthreads();
    }

    #pragma unroll
    for (int i = 0; i < TM; i++) {
        int m = bm + ty*TM + i;
        #pragma unroll
        for (int j = 0; j < TN; j++) {
            int n = bn + tx*TN + j;
            float v = acc[i][j];
            if (MODE == 0) {
                v += bias[n];
                if (n < D_INNER) out0[(size_t)m * D_INNER + n] = v;
                else             out1[(size_t)m * D_INNER + (n - D_INNER)] = silu_f(v);
            } else if (MODE == 1) {
                out0[(size_t)m * N + n] = v;
            } else if (MODE == 2) {
                out0[(size_t)m * N + n] = softplus_f(v + bias[n]);
            } else {
                out0[(size_t)m * N + n] = v + bias[n];
            }
        }
    }
}

// ---------------------------------------------------------------------------
// Causal depthwise conv (4 taps, left pad 3) + SiLU.  Layout (b, l, c).
// ---------------------------------------------------------------------------
__global__ __launch_bounds__(256)
void conv_silu_kernel(const float* __restrict__ xpre,
                      const float* __restrict__ conv_w,
                      const float* __restrict__ conv_b,
                      float* __restrict__ xb)
{
    int idx = blockIdx.x * blockDim.x + threadIdx.x;  // B*L*D_INNER
    int c = idx % D_INNER;
    int l = (idx / D_INNER) % SEQLEN;
    int b = idx / (D_INNER * SEQLEN);
    const float* base = xpre + (size_t)b * SEQLEN * D_INNER + c;
    float w0 = conv_w[c*4+0], w1 = conv_w[c*4+1];
    float w2 = conv_w[c*4+2], w3 = conv_w[c*4+3];
    float acc = conv_b[c];
    if (l >= 3) acc += w0 * base[(l-3) * D_INNER];
    if (l >= 2) acc += w1 * base[(l-2) * D_INNER];
    if (l >= 1) acc += w2 * base[(l-1) * D_INNER];
    acc += w3 * base[l * D_INNER];
    xb[idx] = silu_f(acc);
}

// ---------------------------------------------------------------------------
// Selective scan: one thread per (b, d) channel, 16 states in registers.
// Fuses the epilogue: out = (y + x*D[d]) * silu(z), written in-place over z.
// ---------------------------------------------------------------------------
__global__ __launch_bounds__(256)
void scan_kernel(const float* __restrict__ dt,    // (B,L,D_INNER)
                 const float* __restrict__ xdbl,  // (B,L,96): [64:80]=B [80:96]=C
                 const float* __restrict__ xb,    // (B,L,D_INNER)
                 const float* __restrict__ A_log, // (D_INNER,16)
                 const float* __restrict__ Dvec,  // (D_INNER)
                 float* __restrict__ zio)         // in: silu(z); out: gated y
{
    int idx = blockIdx.x * blockDim.x + threadIdx.x;  // 0 .. B*D_INNER
    int d = idx % D_INNER;
    int b = idx / D_INNER;

    float Arow[D_STATE];
    #pragma unroll
    for (int s = 0; s < D_STATE; s++) Arow[s] = -__expf(A_log[d*D_STATE + s]);
    float Dd = Dvec[d];
    float h[D_STATE];
    #pragma unroll
    for (int s = 0; s < D_STATE; s++) h[s] = 0.0f;

    const float* dtp = dt + (size_t)b * SEQLEN * D_INNER + d;
    const float* xp  = xb + (size_t)b * SEQLEN * D_INNER + d;
    float*       zp  = zio + (size_t)b * SEQLEN * D_INNER + d;
    const float* bc  = xdbl + (size_t)b * SEQLEN * 96 + DT_RANK;

    for (int l = 0; l < SEQLEN; l++) {
        float dtv = dtp[l * D_INNER];
        float xv  = xp[l * D_INNER];
        float dx  = dtv * xv;
        const float* bcl = bc + l * 96;
        float y = 0.0f;
        #pragma unroll
        for (int s = 0; s < D_STATE; s++) {
            float dA = __expf(dtv * Arow[s]);
            h[s] = dA * h[s] + dx * bcl[s];
            y += h[s] * bcl[D_STATE + s];
        }
        float zv = zp[l * D_INNER];
        zp[l * D_INNER] = (y + xv * Dd) * zv;
    }
}

// ---------------------------------------------------------------------------
extern "C" void kernel_launch(void* const* d_in, const int* in_sizes, int n_in,
                              void* d_out, int out_size, void* d_ws, size_t ws_size,
                              hipStream_t stream)
{
    const float* x          = (const float*)d_in[0];
    const float* in_proj_w  = (const float*)d_in[1];
    const float* in_proj_b  = (const float*)d_in[2];
    const float* conv_w     = (const float*)d_in[3];
    const float* conv_b     = (const float*)d_in[4];
    const float* x_proj_w   = (const float*)d_in[5];
    const float* dt_proj_w  = (const float*)d_in[6];
    const float* dt_proj_b  = (const float*)d_in[7];
    const float* A_log      = (const float*)d_in[8];
    const float* Dv         = (const float*)d_in[9];
    const float* out_proj_w = (const float*)d_in[10];
    const float* out_proj_b = (const float*)d_in[11];
    float* out = (float*)d_out;

    // workspace layout (floats):
    //   xpre : M_TOTAL*D_INNER  (pre-conv x branch; later reused as dt)
    //   xb   : M_TOTAL*D_INNER  (post conv+silu)
    //   zb   : M_TOTAL*D_INNER  (silu(z); scan overwrites with gated y)
    //   xdbl : M_TOTAL*96
    float* ws   = (float*)d_ws;
    float* xpre = ws;
    float* xb   = ws + (size_t)M_TOTAL * D_INNER;
    float* zb   = ws + (size_t)2 * M_TOTAL * D_INNER;
    float* xdbl = ws + (size_t)3 * M_TOTAL * D_INNER;
    float* dt   = xpre;  // reuse: xpre dead after conv, dt written after

    // 1) in_proj: xz = x @ in_proj_w^T + b ; split into xpre / silu(z)
    {
        dim3 grid((2*D_INNER)/64, M_TOTAL/64);
        gemm_nt<64,64,16,4,4,0><<<grid, 256, 0, stream>>>(
            x, D_MODEL, in_proj_w, D_MODEL, in_proj_b,
            xpre, zb, M_TOTAL, 2*D_INNER, D_MODEL);
    }
    // 2) causal depthwise conv + silu
    conv_silu_kernel<<<(BATCH*SEQLEN*D_INNER)/256, 256, 0, stream>>>(
        xpre, conv_w, conv_b, xb);
    // 3) x_proj: xdbl = xb @ x_proj_w^T   (N = 96)
    {
        dim3 grid(96/32, M_TOTAL/64);
        gemm_nt<64,32,16,4,4,1><<<grid, 128, 0, stream>>>(
            xb, D_INNER, x_proj_w, D_INNER, nullptr,
            xdbl, nullptr, M_TOTAL, 96, D_INNER);
    }
    // 4) dt_proj: dt = softplus(xdbl[:, :64] @ dt_proj_w^T + b)
    {
        dim3 grid(D_INNER/64, M_TOTAL/64);
        gemm_nt<64,64,16,4,4,2><<<grid, 256, 0, stream>>>(
            xdbl, 96, dt_proj_w, DT_RANK, dt_proj_b,
            dt, nullptr, M_TOTAL, D_INNER, DT_RANK);
    }
    // 5) selective scan (+D skip, +z gate) — overwrites zb with gated y
    scan_kernel<<<(BATCH*D_INNER)/256, 256, 0, stream>>>(
        dt, xdbl, xb, A_log, Dv, zb);
    // 6) out_proj: out = ygated @ out_proj_w^T + b
    {
        dim3 grid(D_MODEL/64, M_TOTAL/64);
        gemm_nt<64,64,16,4,4,3><<<grid, 256, 0, stream>>>(
            zb, D_INNER, out_proj_w, D_INNER, out_proj_b,
            out, nullptr, M_TOTAL, D_MODEL, D_INNER);
    }
}

// Round 2
// 1231.689 us; speedup vs baseline: 1.1616x; 1.1616x over previous
//
#include <hip/hip_runtime.h>
#include <math.h>

#define D_STATE 16
#define D_CONV 4
#define DT_RANK 64
#define D_INNER 2048
#define D_MODEL 1024
#define BATCH 2
#define SEQLEN 1024
#define M_TOTAL (BATCH*SEQLEN)  // 2048

__device__ __forceinline__ float silu_f(float x) {
    return x / (1.0f + __expf(-x));
}
__device__ __forceinline__ float softplus_f(float x) {
    // jax.nn.softplus = logaddexp(x, 0) = max(x,0) + log1p(exp(-|x|))
    return fmaxf(x, 0.0f) + log1pf(__expf(-fabsf(x)));
}

// ---------------------------------------------------------------------------
// Generic NT GEMM: C[m,n] = sum_k A[m*lda+k] * B[n*ldb+k]   (both K-contiguous)
// MODE 0: v=acc+bias[n]; n<D_INNER -> out0[m*D_INNER+n]=v else out1[...]=silu(v)
// MODE 1: out0[m*N+n] = acc
// MODE 2: out0[m*N+n] = softplus(acc + bias[n])
// MODE 3: out0[m*N+n] = acc + bias[n]
// ---------------------------------------------------------------------------
template<int BM, int BN, int BK, int TM, int TN, int MODE>
__global__ __launch_bounds__((BM/TM)*(BN/TN))
void gemm_nt(const float* __restrict__ A, int lda,
             const float* __restrict__ B, int ldb,
             const float* __restrict__ bias,
             float* __restrict__ out0, float* __restrict__ out1,
             int M, int N, int K)
{
    constexpr int THREADS = (BM/TM)*(BN/TN);
    __shared__ float As[BK][BM+4];
    __shared__ float Bs[BK][BN+4];
    const int tid = threadIdx.x;
    const int bm = blockIdx.y * BM;
    const int bn = blockIdx.x * BN;
    const int tx = tid % (BN/TN);   // n-direction
    const int ty = tid / (BN/TN);   // m-direction

    float acc[TM][TN];
    #pragma unroll
    for (int i = 0; i < TM; i++)
        #pragma unroll
        for (int j = 0; j < TN; j++) acc[i][j] = 0.0f;

    constexpr int F4_PER_ROW = BK / 4;             // float4 chunks per K-row
    constexpr int A_ROWS_PER_ITER = THREADS / F4_PER_ROW;
    constexpr int B_ROWS_PER_ITER = THREADS / F4_PER_ROW;

    for (int kt = 0; kt < K; kt += BK) {
        #pragma unroll
        for (int r = 0; r < BM; r += A_ROWS_PER_ITER) {
            int row = r + tid / F4_PER_ROW;
            int kc  = (tid % F4_PER_ROW) * 4;
            float4 v = *(const float4*)(A + (size_t)(bm + row) * lda + kt + kc);
            As[kc+0][row] = v.x; As[kc+1][row] = v.y;
            As[kc+2][row] = v.z; As[kc+3][row] = v.w;
        }
        #pragma unroll
        for (int r = 0; r < BN; r += B_ROWS_PER_ITER) {
            int row = r + tid / F4_PER_ROW;
            int kc  = (tid % F4_PER_ROW) * 4;
            float4 v = *(const float4*)(B + (size_t)(bn + row) * ldb + kt + kc);
            Bs[kc+0][row] = v.x; Bs[kc+1][row] = v.y;
            Bs[kc+2][row] = v.z; Bs[kc+3][row] = v.w;
        }
        __syncthreads();
        #pragma unroll
        for (int k = 0; k < BK; k++) {
            float ra[TM], rb[TN];
            #pragma unroll
            for (int i = 0; i < TM; i++) ra[i] = As[k][ty*TM + i];
            #pragma unroll
            for (int j = 0; j < TN; j++) rb[j] = Bs[k][tx*TN + j];
            #pragma unroll
            for (int i = 0; i < TM; i++)
                #pragma unroll
                for (int j = 0; j < TN; j++) acc[i][j] += ra[i] * rb[j];
        }
        __syncthreads();
    }

    #pragma unroll
    for (int i = 0; i < TM; i++) {
        int m = bm + ty*TM + i;
        #pragma unroll
        for (int j = 0; j < TN; j++) {
            int n = bn + tx*TN + j;
            float v = acc[i][j];
            if (MODE == 0) {
                v += bias[n];
                if (n < D_INNER) out0[(size_t)m * D_INNER + n] = v;
                else             out1[(size_t)m * D_INNER + (n - D_INNER)] = silu_f(v);
            } else if (MODE == 1) {
                out0[(size_t)m * N + n] = v;
            } else if (MODE == 2) {
                out0[(size_t)m * N + n] = softplus_f(v + bias[n]);
            } else {
                out0[(size_t)m * N + n] = v + bias[n];
            }
        }
    }
}

// ---------------------------------------------------------------------------
// Causal depthwise conv (4 taps, left pad 3) + SiLU.  Layout (b, l, c).
// ---------------------------------------------------------------------------
__global__ __launch_bounds__(256)
void conv_silu_kernel(const float* __restrict__ xpre,
                      const float* __restrict__ conv_w,
                      const float* __restrict__ conv_b,
                      float* __restrict__ xb)
{
    int idx = blockIdx.x * blockDim.x + threadIdx.x;  // B*L*D_INNER
    int c = idx % D_INNER;
    int l = (idx / D_INNER) % SEQLEN;
    int b = idx / (D_INNER * SEQLEN);
    const float* base = xpre + (size_t)b * SEQLEN * D_INNER + c;
    float w0 = conv_w[c*4+0], w1 = conv_w[c*4+1];
    float w2 = conv_w[c*4+2], w3 = conv_w[c*4+3];
    float acc = conv_b[c];
    if (l >= 3) acc += w0 * base[(l-3) * D_INNER];
    if (l >= 2) acc += w1 * base[(l-2) * D_INNER];
    if (l >= 1) acc += w2 * base[(l-1) * D_INNER];
    acc += w3 * base[l * D_INNER];
    xb[idx] = silu_f(acc);
}

// ---------------------------------------------------------------------------
// Selective scan, state-parallel: one thread per (b, d, s).
// 16 lanes (one per state) cooperate on a channel; y = sum_s h*C via
// __shfl_xor butterfly over the 16-lane group. Lane s==0 applies the
// D-skip and z-gate and writes the result in-place over silu(z).
// ---------------------------------------------------------------------------
__global__ __launch_bounds__(256)
void scan_kernel(const float* __restrict__ dt,    // (B,L,D_INNER)
                 const float* __restrict__ xdbl,  // (B,L,96): [64:80]=B [80:96]=C
                 const float* __restrict__ xb,    // (B,L,D_INNER)
                 const float* __restrict__ A_log, // (D_INNER,16)
                 const float* __restrict__ Dvec,  // (D_INNER)
                 float* __restrict__ zio)         // in: silu(z); out: gated y
{
    int tid = blockIdx.x * blockDim.x + threadIdx.x;  // 0 .. B*D_INNER*16
    int s  = tid & (D_STATE - 1);
    int gd = tid >> 4;                 // 0 .. B*D_INNER
    int d  = gd & (D_INNER - 1);
    int b  = gd >> 11;

    float As = -__expf(A_log[d * D_STATE + s]);
    float Dd = Dvec[d];
    float h = 0.0f;

    const float* dtp = dt  + (size_t)b * SEQLEN * D_INNER + d;
    const float* xp  = xb  + (size_t)b * SEQLEN * D_INNER + d;
    float*       zp  = zio + (size_t)b * SEQLEN * D_INNER + d;
    const float* bc  = xdbl + (size_t)b * SEQLEN * 96 + DT_RANK + s;

    #pragma unroll 4
    for (int l = 0; l < SEQLEN; l++) {
        float dtv = dtp[l * D_INNER];   // broadcast within 16-lane group
        float xv  = xp[l * D_INNER];
        float Bv  = bc[l * 96];
        float Cv  = bc[l * 96 + D_STATE];
        float dA  = __expf(dtv * As);
        h = dA * h + (dtv * xv) * Bv;
        float p = h * Cv;
        p += __shfl_xor(p, 1);
        p += __shfl_xor(p, 2);
        p += __shfl_xor(p, 4);
        p += __shfl_xor(p, 8);
        if (s == 0) {
            float zv = zp[l * D_INNER];
            zp[l * D_INNER] = (p + xv * Dd) * zv;
        }
    }
}

// ---------------------------------------------------------------------------
extern "C" void kernel_launch(void* const* d_in, const int* in_sizes, int n_in,
                              void* d_out, int out_size, void* d_ws, size_t ws_size,
                              hipStream_t stream)
{
    const float* x          = (const float*)d_in[0];
    const float* in_proj_w  = (const float*)d_in[1];
    const float* in_proj_b  = (const float*)d_in[2];
    const float* conv_w     = (const float*)d_in[3];
    const float* conv_b     = (const float*)d_in[4];
    const float* x_proj_w   = (const float*)d_in[5];
    const float* dt_proj_w  = (const float*)d_in[6];
    const float* dt_proj_b  = (const float*)d_in[7];
    const float* A_log      = (const float*)d_in[8];
    const float* Dv         = (const float*)d_in[9];
    const float* out_proj_w = (const float*)d_in[10];
    const float* out_proj_b = (const float*)d_in[11];
    float* out = (float*)d_out;

    // workspace layout (floats):
    //   xpre : M_TOTAL*D_INNER  (pre-conv x branch; later reused as dt)
    //   xb   : M_TOTAL*D_INNER  (post conv+silu)
    //   zb   : M_TOTAL*D_INNER  (silu(z); scan overwrites with gated y)
    //   xdbl : M_TOTAL*96
    float* ws   = (float*)d_ws;
    float* xpre = ws;
    float* xb   = ws + (size_t)M_TOTAL * D_INNER;
    float* zb   = ws + (size_t)2 * M_TOTAL * D_INNER;
    float* xdbl = ws + (size_t)3 * M_TOTAL * D_INNER;
    float* dt   = xpre;  // reuse: xpre dead after conv, dt written after

    // 1) in_proj: xz = x @ in_proj_w^T + b ; split into xpre / silu(z)
    {
        dim3 grid((2*D_INNER)/64, M_TOTAL/64);
        gemm_nt<64,64,16,4,4,0><<<grid, 256, 0, stream>>>(
            x, D_MODEL, in_proj_w, D_MODEL, in_proj_b,
            xpre, zb, M_TOTAL, 2*D_INNER, D_MODEL);
    }
    // 2) causal depthwise conv + silu
    conv_silu_kernel<<<(BATCH*SEQLEN*D_INNER)/256, 256, 0, stream>>>(
        xpre, conv_w, conv_b, xb);
    // 3) x_proj: xdbl = xb @ x_proj_w^T   (N = 96)
    {
        dim3 grid(96/32, M_TOTAL/64);
        gemm_nt<64,32,16,4,4,1><<<grid, 128, 0, stream>>>(
            xb, D_INNER, x_proj_w, D_INNER, nullptr,
            xdbl, nullptr, M_TOTAL, 96, D_INNER);
    }
    // 4) dt_proj: dt = softplus(xdbl[:, :64] @ dt_proj_w^T + b)
    {
        dim3 grid(D_INNER/64, M_TOTAL/64);
        gemm_nt<64,64,16,4,4,2><<<grid, 256, 0, stream>>>(
            xdbl, 96, dt_proj_w, DT_RANK, dt_proj_b,
            dt, nullptr, M_TOTAL, D_INNER, DT_RANK);
    }
    // 5) selective scan (+D skip, +z gate), state-parallel — overwrites zb
    scan_kernel<<<(BATCH*D_INNER*D_STATE)/256, 256, 0, stream>>>(
        dt, xdbl, xb, A_log, Dv, zb);
    // 6) out_proj: out = ygated @ out_proj_w^T + b
    {
        dim3 grid(D_MODEL/64, M_TOTAL/64);
        gemm_nt<64,64,16,4,4,3><<<grid, 256, 0, stream>>>(
            zb, D_INNER, out_proj_w, D_INNER, out_proj_b,
            out, nullptr, M_TOTAL, D_MODEL, D_INNER);
    }
}

// Round 3
// 696.968 us; speedup vs baseline: 2.0527x; 1.7672x over previous
//
#include <hip/hip_runtime.h>
#include <math.h>

#define D_STATE 16
#define D_CONV 4
#define DT_RANK 64
#define D_INNER 2048
#define D_MODEL 1024
#define BATCH 2
#define SEQLEN 1024
#define M_TOTAL (BATCH*SEQLEN)  // 2048

#define LC 64                    // chunk length
#define NCHUNK (SEQLEN/LC)       // 16
#define CH 16                    // channels per scan block

__device__ __forceinline__ float silu_f(float x) {
    return x / (1.0f + __expf(-x));
}
__device__ __forceinline__ float softplus_f(float x) {
    return fmaxf(x, 0.0f) + log1pf(__expf(-fabsf(x)));
}

// ---------------------------------------------------------------------------
// Generic NT GEMM: C[m,n] = sum_k A[m*lda+k] * B[n*ldb+k]   (both K-contiguous)
// MODE 0: v=acc+bias[n]; n<D_INNER -> out0[m*D_INNER+n]=v else out1[...]=silu(v)
// MODE 1: out0[m*N+n] = acc
// MODE 2: out0[m*N+n] = softplus(acc + bias[n])
// MODE 3: out0[m*N+n] = acc + bias[n]
// ---------------------------------------------------------------------------
template<int BM, int BN, int BK, int TM, int TN, int MODE>
__global__ __launch_bounds__((BM/TM)*(BN/TN))
void gemm_nt(const float* __restrict__ A, int lda,
             const float* __restrict__ B, int ldb,
             const float* __restrict__ bias,
             float* __restrict__ out0, float* __restrict__ out1,
             int M, int N, int K)
{
    constexpr int THREADS = (BM/TM)*(BN/TN);
    __shared__ float As[BK][BM+4];
    __shared__ float Bs[BK][BN+4];
    const int tid = threadIdx.x;
    const int bm = blockIdx.y * BM;
    const int bn = blockIdx.x * BN;
    const int tx = tid % (BN/TN);
    const int ty = tid / (BN/TN);

    float acc[TM][TN];
    #pragma unroll
    for (int i = 0; i < TM; i++)
        #pragma unroll
        for (int j = 0; j < TN; j++) acc[i][j] = 0.0f;

    constexpr int F4_PER_ROW = BK / 4;
    constexpr int A_ROWS_PER_ITER = THREADS / F4_PER_ROW;
    constexpr int B_ROWS_PER_ITER = THREADS / F4_PER_ROW;

    for (int kt = 0; kt < K; kt += BK) {
        #pragma unroll
        for (int r = 0; r < BM; r += A_ROWS_PER_ITER) {
            int row = r + tid / F4_PER_ROW;
            int kc  = (tid % F4_PER_ROW) * 4;
            float4 v = *(const float4*)(A + (size_t)(bm + row) * lda + kt + kc);
            As[kc+0][row] = v.x; As[kc+1][row] = v.y;
            As[kc+2][row] = v.z; As[kc+3][row] = v.w;
        }
        #pragma unroll
        for (int r = 0; r < BN; r += B_ROWS_PER_ITER) {
            int row = r + tid / F4_PER_ROW;
            int kc  = (tid % F4_PER_ROW) * 4;
            float4 v = *(const float4*)(B + (size_t)(bn + row) * ldb + kt + kc);
            Bs[kc+0][row] = v.x; Bs[kc+1][row] = v.y;
            Bs[kc+2][row] = v.z; Bs[kc+3][row] = v.w;
        }
        __syncthreads();
        #pragma unroll
        for (int k = 0; k < BK; k++) {
            float ra[TM], rb[TN];
            #pragma unroll
            for (int i = 0; i < TM; i++) ra[i] = As[k][ty*TM + i];
            #pragma unroll
            for (int j = 0; j < TN; j++) rb[j] = Bs[k][tx*TN + j];
            #pragma unroll
            for (int i = 0; i < TM; i++)
                #pragma unroll
                for (int j = 0; j < TN; j++) acc[i][j] += ra[i] * rb[j];
        }
        __syncthreads();
    }

    #pragma unroll
    for (int i = 0; i < TM; i++) {
        int m = bm + ty*TM + i;
        #pragma unroll
        for (int j = 0; j < TN; j++) {
            int n = bn + tx*TN + j;
            float v = acc[i][j];
            if (MODE == 0) {
                v += bias[n];
                if (n < D_INNER) out0[(size_t)m * D_INNER + n] = v;
                else             out1[(size_t)m * D_INNER + (n - D_INNER)] = silu_f(v);
            } else if (MODE == 1) {
                out0[(size_t)m * N + n] = v;
            } else if (MODE == 2) {
                out0[(size_t)m * N + n] = softplus_f(v + bias[n]);
            } else {
                out0[(size_t)m * N + n] = v + bias[n];
            }
        }
    }
}

// ---------------------------------------------------------------------------
// Causal depthwise conv (4 taps, left pad 3) + SiLU.  Layout (b, l, c).
// ---------------------------------------------------------------------------
__global__ __launch_bounds__(256)
void conv_silu_kernel(const float* __restrict__ xpre,
                      const float* __restrict__ conv_w,
                      const float* __restrict__ conv_b,
                      float* __restrict__ xb)
{
    int idx = blockIdx.x * blockDim.x + threadIdx.x;
    int c = idx % D_INNER;
    int l = (idx / D_INNER) % SEQLEN;
    int b = idx / (D_INNER * SEQLEN);
    const float* base = xpre + (size_t)b * SEQLEN * D_INNER + c;
    float w0 = conv_w[c*4+0], w1 = conv_w[c*4+1];
    float w2 = conv_w[c*4+2], w3 = conv_w[c*4+3];
    float acc = conv_b[c];
    if (l >= 3) acc += w0 * base[(l-3) * D_INNER];
    if (l >= 2) acc += w1 * base[(l-2) * D_INNER];
    if (l >= 1) acc += w2 * base[(l-1) * D_INNER];
    acc += w3 * base[l * D_INNER];
    xb[idx] = silu_f(acc);
}

// ---------------------------------------------------------------------------
// Chunked selective scan.
// The recurrence h_l = a_l h_{l-1} + b_l is linear in h, so per chunk c:
//   h_end = P_c * h_in + hloc_c,  P_c = prod a_l,  hloc = scan with h_in=0.
// phase1: per-chunk (P, hloc).  carry: tiny scan over 16 chunks -> h_in.
// phase2: re-run with true h_in, fused C-dot + D-skip + z-gate.
// Block = 16 channels x 16 states; LDS-staged tiles, coalesced float4.
// ---------------------------------------------------------------------------
__global__ __launch_bounds__(256)
void scan_phase1(const float* __restrict__ dt,
                 const float* __restrict__ xdbl,
                 const float* __restrict__ xb,
                 const float* __restrict__ A_log,
                 float* __restrict__ Pbuf, float* __restrict__ hbuf)
{
    int bx = blockIdx.x;
    int dg = bx & 127;           // channel group
    int c  = (bx >> 7) & (NCHUNK - 1);
    int b  = bx >> 11;
    int d0 = dg * CH;
    int t  = threadIdx.x;
    int s  = t & 15, ch = t >> 4;
    int d  = d0 + ch;
    int l0 = c * LC;

    __shared__ __align__(16) float dt_t[LC][CH];
    __shared__ __align__(16) float x_t[LC][CH];
    __shared__ __align__(16) float B_t[LC][D_STATE];
    {
        int row = t >> 2, c4 = (t & 3) * 4;
        size_t rbase = (size_t)(b * SEQLEN + l0 + row);
        *(float4*)&dt_t[row][c4] = *(const float4*)(dt   + rbase * D_INNER + d0 + c4);
        *(float4*)&x_t[row][c4]  = *(const float4*)(xb   + rbase * D_INNER + d0 + c4);
        *(float4*)&B_t[row][c4]  = *(const float4*)(xdbl + rbase * 96 + DT_RANK + c4);
    }
    float As = -__expf(A_log[d * D_STATE + s]);
    __syncthreads();

    float h = 0.0f, P = 1.0f;
    #pragma unroll
    for (int l = 0; l < LC; l++) {
        float dtv = dt_t[l][ch];
        float a = __expf(dtv * As);
        h = a * h + (dtv * x_t[l][ch]) * B_t[l][s];
        P *= a;
    }
    size_t idx = (((size_t)(b * NCHUNK + c)) * D_INNER + d) * D_STATE + s;
    Pbuf[idx] = P;
    hbuf[idx] = h;
}

__global__ __launch_bounds__(256)
void scan_carry(float* __restrict__ Pbuf, const float* __restrict__ hbuf)
{
    int t = blockIdx.x * blockDim.x + threadIdx.x;   // 0 .. B*D_INNER*16
    int s = t & 15;
    int d = (t >> 4) & (D_INNER - 1);
    int b = t >> 15;
    float h = 0.0f;
    #pragma unroll
    for (int c = 0; c < NCHUNK; c++) {
        size_t idx = (((size_t)(b * NCHUNK + c)) * D_INNER + d) * D_STATE + s;
        float Pc = Pbuf[idx];
        float hl = hbuf[idx];
        Pbuf[idx] = h;              // overwrite P with h_in for this chunk
        h = Pc * h + hl;
    }
}

__global__ __launch_bounds__(256)
void scan_phase2(const float* __restrict__ dt,
                 const float* __restrict__ xdbl,
                 const float* __restrict__ xb,
                 const float* __restrict__ A_log,
                 const float* __restrict__ Dvec,
                 const float* __restrict__ hinbuf,   // == Pbuf after carry
                 float* __restrict__ zio)            // in: silu(z); out: gated y
{
    int bx = blockIdx.x;
    int dg = bx & 127;
    int c  = (bx >> 7) & (NCHUNK - 1);
    int b  = bx >> 11;
    int d0 = dg * CH;
    int t  = threadIdx.x;
    int s  = t & 15, ch = t >> 4;
    int d  = d0 + ch;
    int l0 = c * LC;

    __shared__ __align__(16) float dt_t[LC][CH];
    __shared__ __align__(16) float x_t[LC][CH];
    __shared__ __align__(16) float z_t[LC][CH];
    __shared__ __align__(16) float B_t[LC][D_STATE];
    __shared__ __align__(16) float C_t[LC][D_STATE];
    __shared__ __align__(16) float y_t[LC][CH];
    {
        int row = t >> 2, c4 = (t & 3) * 4;
        size_t rbase = (size_t)(b * SEQLEN + l0 + row);
        *(float4*)&dt_t[row][c4] = *(const float4*)(dt   + rbase * D_INNER + d0 + c4);
        *(float4*)&x_t[row][c4]  = *(const float4*)(xb   + rbase * D_INNER + d0 + c4);
        *(float4*)&z_t[row][c4]  = *(const float4*)(zio  + rbase * D_INNER + d0 + c4);
        *(float4*)&B_t[row][c4]  = *(const float4*)(xdbl + rbase * 96 + DT_RANK + c4);
        *(float4*)&C_t[row][c4]  = *(const float4*)(xdbl + rbase * 96 + DT_RANK + D_STATE + c4);
    }
    float As = -__expf(A_log[d * D_STATE + s]);
    float Dd = Dvec[d];
    size_t idx = (((size_t)(b * NCHUNK + c)) * D_INNER + d) * D_STATE + s;
    float h = hinbuf[idx];
    __syncthreads();

    #pragma unroll
    for (int l = 0; l < LC; l++) {
        float dtv = dt_t[l][ch];
        float xv  = x_t[l][ch];
        float a = __expf(dtv * As);
        h = a * h + (dtv * xv) * B_t[l][s];
        float p = h * C_t[l][s];
        p += __shfl_xor(p, 1);
        p += __shfl_xor(p, 2);
        p += __shfl_xor(p, 4);
        p += __shfl_xor(p, 8);
        if (s == 0) y_t[l][ch] = (p + xv * Dd) * z_t[l][ch];
    }
    __syncthreads();
    {
        int row = t >> 2, c4 = (t & 3) * 4;
        size_t rbase = (size_t)(b * SEQLEN + l0 + row);
        *(float4*)(zio + rbase * D_INNER + d0 + c4) = *(float4*)&y_t[row][c4];
    }
}

// ---------------------------------------------------------------------------
extern "C" void kernel_launch(void* const* d_in, const int* in_sizes, int n_in,
                              void* d_out, int out_size, void* d_ws, size_t ws_size,
                              hipStream_t stream)
{
    const float* x          = (const float*)d_in[0];
    const float* in_proj_w  = (const float*)d_in[1];
    const float* in_proj_b  = (const float*)d_in[2];
    const float* conv_w     = (const float*)d_in[3];
    const float* conv_b     = (const float*)d_in[4];
    const float* x_proj_w   = (const float*)d_in[5];
    const float* dt_proj_w  = (const float*)d_in[6];
    const float* dt_proj_b  = (const float*)d_in[7];
    const float* A_log      = (const float*)d_in[8];
    const float* Dv         = (const float*)d_in[9];
    const float* out_proj_w = (const float*)d_in[10];
    const float* out_proj_b = (const float*)d_in[11];
    float* out = (float*)d_out;

    float* ws   = (float*)d_ws;
    float* xpre = ws;
    float* xb   = ws + (size_t)M_TOTAL * D_INNER;
    float* zb   = ws + (size_t)2 * M_TOTAL * D_INNER;
    float* xdbl = ws + (size_t)3 * M_TOTAL * D_INNER;
    float* dt   = xpre;  // reuse: xpre dead after conv

    // Scan scratch lives in d_out (8.4 MB, dead until final GEMM overwrites):
    //   Pbuf: B*NCHUNK*D_INNER*16 = 1.05M floats; hbuf: same.  Total = out_size.
    float* Pbuf = out;
    float* hbuf = out + (size_t)BATCH * NCHUNK * D_INNER * D_STATE;

    // 1) in_proj: xz = x @ in_proj_w^T + b ; split into xpre / silu(z)
    {
        dim3 grid((2*D_INNER)/64, M_TOTAL/64);
        gemm_nt<64,64,16,4,4,0><<<grid, 256, 0, stream>>>(
            x, D_MODEL, in_proj_w, D_MODEL, in_proj_b,
            xpre, zb, M_TOTAL, 2*D_INNER, D_MODEL);
    }
    // 2) causal depthwise conv + silu
    conv_silu_kernel<<<(BATCH*SEQLEN*D_INNER)/256, 256, 0, stream>>>(
        xpre, conv_w, conv_b, xb);
    // 3) x_proj: xdbl = xb @ x_proj_w^T   (N = 96)
    {
        dim3 grid(96/32, M_TOTAL/64);
        gemm_nt<64,32,16,4,4,1><<<grid, 128, 0, stream>>>(
            xb, D_INNER, x_proj_w, D_INNER, nullptr,
            xdbl, nullptr, M_TOTAL, 96, D_INNER);
    }
    // 4) dt_proj: dt = softplus(xdbl[:, :64] @ dt_proj_w^T + b)
    {
        dim3 grid(D_INNER/64, M_TOTAL/64);
        gemm_nt<64,64,16,4,4,2><<<grid, 256, 0, stream>>>(
            xdbl, 96, dt_proj_w, DT_RANK, dt_proj_b,
            dt, nullptr, M_TOTAL, D_INNER, DT_RANK);
    }
    // 5) chunked selective scan (+D skip, +z gate) — overwrites zb
    {
        int nblk = BATCH * NCHUNK * (D_INNER / CH);   // 4096
        scan_phase1<<<nblk, 256, 0, stream>>>(dt, xdbl, xb, A_log, Pbuf, hbuf);
        scan_carry<<<(BATCH*D_INNER*D_STATE)/256, 256, 0, stream>>>(Pbuf, hbuf);
        scan_phase2<<<nblk, 256, 0, stream>>>(dt, xdbl, xb, A_log, Dv, Pbuf, zb);
    }
    // 6) out_proj: out = ygated @ out_proj_w^T + b
    {
        dim3 grid(D_MODEL/64, M_TOTAL/64);
        gemm_nt<64,64,16,4,4,3><<<grid, 256, 0, stream>>>(
            zb, D_INNER, out_proj_w, D_INNER, out_proj_b,
            out, nullptr, M_TOTAL, D_MODEL, D_INNER);
    }
}

// Round 5
// 431.402 us; speedup vs baseline: 3.3163x; 1.6156x over previous
//
#include <hip/hip_runtime.h>
#include <math.h>

#define D_STATE 16
#define D_CONV 4
#define DT_RANK 64
#define D_INNER 2048
#define D_MODEL 1024
#define BATCH 2
#define SEQLEN 1024
#define M_TOTAL (BATCH*SEQLEN)  // 2048

#define LC 64                    // scan chunk length
#define NCHUNK (SEQLEN/LC)       // 16
#define CH 16                    // channels per scan block

typedef __fp16   h2s_t  __attribute__((ext_vector_type(2)));  // pkrtz result
typedef __fp16   h8s_t  __attribute__((ext_vector_type(8)));  // storage vec
typedef _Float16 half8  __attribute__((ext_vector_type(8)));  // MFMA operand
typedef float    floatx4 __attribute__((ext_vector_type(4)));

union HalfPack { h2s_t h2[4]; h8s_t h8; };

__device__ __forceinline__ float silu_f(float x) {
    return x / (1.0f + __expf(-x));
}
__device__ __forceinline__ float softplus_f(float x) {
    return fmaxf(x, 0.0f) + log1pf(__expf(-fabsf(x)));
}

// ---------------------------------------------------------------------------
// f16-MFMA NT GEMM, f32 in/out, cast-on-stage (pkrtz -> __fp16 LDS tiles).
// C[m,n] = sum_k A[m*lda+k] * B[n*ldb+k]; f32 accumulate via MFMA.
// MODE 0: v=acc+bias[n]; n<D_INNER -> out0[m*D_INNER+n]=v else out1=silu(v)
// MODE 3: out0[m*N+n] = acc + bias[n]
// Tile 128x128x32, 256 threads (4 waves), each wave 64x64 via 4x4 MFMA tiles.
// LDS rows padded to 40 halfs (80B): frag reads land 2-way aliased (free).
// ---------------------------------------------------------------------------
template<int MODE>
__global__ __launch_bounds__(256)
void gemm_mfma(const float* __restrict__ A, int lda,
               const float* __restrict__ B, int ldb,
               const float* __restrict__ bias,
               float* __restrict__ out0, float* __restrict__ out1,
               int N, int K)
{
    constexpr int BM = 128, BN = 128, BK = 32;
    constexpr int LDH = 40;  // padded halfs per row
    __shared__ __fp16 As[BM * LDH];
    __shared__ __fp16 Bs[BN * LDH];

    const int tid  = threadIdx.x;
    const int bm   = blockIdx.y * BM;
    const int bn   = blockIdx.x * BN;
    const int wave = tid >> 6;
    const int lane = tid & 63;
    const int wm   = (wave >> 1) * 64;   // wave m-offset within tile
    const int wn   = (wave & 1) * 64;    // wave n-offset within tile
    const int fr   = lane & 15;          // frag row (A: m, B: n)
    const int fk   = (lane >> 4) * 8;    // frag k offset

    // staging map: thread covers rows {tid>>2, tid>>2 + 64}, k-chunk (tid&3)*8
    const int srow = tid >> 2;
    const int skc  = (tid & 3) * 8;

    floatx4 zero = {0.f, 0.f, 0.f, 0.f};
    floatx4 acc[4][4];
    #pragma unroll
    for (int i = 0; i < 4; i++)
        #pragma unroll
        for (int j = 0; j < 4; j++) acc[i][j] = zero;

    for (int kt = 0; kt < K; kt += BK) {
        #pragma unroll
        for (int hidx = 0; hidx < 2; hidx++) {
            int row = srow + hidx * 64;
            const float* ga = A + (size_t)(bm + row) * lda + kt + skc;
            float4 a0 = *(const float4*)ga;
            float4 a1 = *(const float4*)(ga + 4);
            HalfPack pa;
            pa.h2[0] = __builtin_amdgcn_cvt_pkrtz(a0.x, a0.y);
            pa.h2[1] = __builtin_amdgcn_cvt_pkrtz(a0.z, a0.w);
            pa.h2[2] = __builtin_amdgcn_cvt_pkrtz(a1.x, a1.y);
            pa.h2[3] = __builtin_amdgcn_cvt_pkrtz(a1.z, a1.w);
            *(h8s_t*)&As[row * LDH + skc] = pa.h8;

            const float* gb = B + (size_t)(bn + row) * ldb + kt + skc;
            float4 b0 = *(const float4*)gb;
            float4 b1 = *(const float4*)(gb + 4);
            HalfPack pb;
            pb.h2[0] = __builtin_amdgcn_cvt_pkrtz(b0.x, b0.y);
            pb.h2[1] = __builtin_amdgcn_cvt_pkrtz(b0.z, b0.w);
            pb.h2[2] = __builtin_amdgcn_cvt_pkrtz(b1.x, b1.y);
            pb.h2[3] = __builtin_amdgcn_cvt_pkrtz(b1.z, b1.w);
            *(h8s_t*)&Bs[row * LDH + skc] = pb.h8;
        }
        __syncthreads();

        half8 af[4], bf[4];
        #pragma unroll
        for (int i = 0; i < 4; i++)
            af[i] = *(half8*)&As[(wm + i*16 + fr) * LDH + fk];
        #pragma unroll
        for (int j = 0; j < 4; j++)
            bf[j] = *(half8*)&Bs[(wn + j*16 + fr) * LDH + fk];
        #pragma unroll
        for (int i = 0; i < 4; i++)
            #pragma unroll
            for (int j = 0; j < 4; j++)
                acc[i][j] = __builtin_amdgcn_mfma_f32_16x16x32_f16(
                    af[i], bf[j], acc[i][j], 0, 0, 0);
        __syncthreads();
    }

    // epilogue: C/D layout col=lane&15, row=(lane>>4)*4+reg
    const int rbase = (lane >> 4) * 4;
    #pragma unroll
    for (int i = 0; i < 4; i++) {
        #pragma unroll
        for (int j = 0; j < 4; j++) {
            int n = bn + wn + j*16 + fr;
            float bv = bias[n];
            #pragma unroll
            for (int r = 0; r < 4; r++) {
                int m = bm + wm + i*16 + rbase + r;
                float v = acc[i][j][r] + bv;
                if (MODE == 0) {
                    if (n < D_INNER) out0[(size_t)m * D_INNER + n] = v;
                    else             out1[(size_t)m * D_INNER + (n - D_INNER)] = silu_f(v);
                } else {
                    out0[(size_t)m * N + n] = v;
                }
            }
        }
    }
}

// ---------------------------------------------------------------------------
// f32 vector-ALU NT GEMM (kept for the small x_proj / dt_proj).
// MODE 1: out0[m*N+n] = acc
// MODE 2: out0[m*N+n] = softplus(acc + bias[n])
// ---------------------------------------------------------------------------
template<int BM, int BN, int BK, int TM, int TN, int MODE>
__global__ __launch_bounds__((BM/TM)*(BN/TN))
void gemm_nt(const float* __restrict__ A, int lda,
             const float* __restrict__ B, int ldb,
             const float* __restrict__ bias,
             float* __restrict__ out0,
             int M, int N, int K)
{
    constexpr int THREADS = (BM/TM)*(BN/TN);
    __shared__ float As[BK][BM+4];
    __shared__ float Bs[BK][BN+4];
    const int tid = threadIdx.x;
    const int bm = blockIdx.y * BM;
    const int bn = blockIdx.x * BN;
    const int tx = tid % (BN/TN);
    const int ty = tid / (BN/TN);

    float acc[TM][TN];
    #pragma unroll
    for (int i = 0; i < TM; i++)
        #pragma unroll
        for (int j = 0; j < TN; j++) acc[i][j] = 0.0f;

    constexpr int F4_PER_ROW = BK / 4;
    constexpr int A_ROWS_PER_ITER = THREADS / F4_PER_ROW;
    constexpr int B_ROWS_PER_ITER = THREADS / F4_PER_ROW;

    for (int kt = 0; kt < K; kt += BK) {
        #pragma unroll
        for (int r = 0; r < BM; r += A_ROWS_PER_ITER) {
            int row = r + tid / F4_PER_ROW;
            int kc  = (tid % F4_PER_ROW) * 4;
            float4 v = *(const float4*)(A + (size_t)(bm + row) * lda + kt + kc);
            As[kc+0][row] = v.x; As[kc+1][row] = v.y;
            As[kc+2][row] = v.z; As[kc+3][row] = v.w;
        }
        #pragma unroll
        for (int r = 0; r < BN; r += B_ROWS_PER_ITER) {
            int row = r + tid / F4_PER_ROW;
            int kc  = (tid % F4_PER_ROW) * 4;
            float4 v = *(const float4*)(B + (size_t)(bn + row) * ldb + kt + kc);
            Bs[kc+0][row] = v.x; Bs[kc+1][row] = v.y;
            Bs[kc+2][row] = v.z; Bs[kc+3][row] = v.w;
        }
        __syncthreads();
        #pragma unroll
        for (int k = 0; k < BK; k++) {
            float ra[TM], rb[TN];
            #pragma unroll
            for (int i = 0; i < TM; i++) ra[i] = As[k][ty*TM + i];
            #pragma unroll
            for (int j = 0; j < TN; j++) rb[j] = Bs[k][tx*TN + j];
            #pragma unroll
            for (int i = 0; i < TM; i++)
                #pragma unroll
                for (int j = 0; j < TN; j++) acc[i][j] += ra[i] * rb[j];
        }
        __syncthreads();
    }

    #pragma unroll
    for (int i = 0; i < TM; i++) {
        int m = bm + ty*TM + i;
        #pragma unroll
        for (int j = 0; j < TN; j++) {
            int n = bn + tx*TN + j;
            float v = acc[i][j];
            if (MODE == 1) out0[(size_t)m * N + n] = v;
            else           out0[(size_t)m * N + n] = softplus_f(v + bias[n]);
        }
    }
}

// ---------------------------------------------------------------------------
// Causal depthwise conv (4 taps, left pad 3) + SiLU.  Layout (b, l, c).
// ---------------------------------------------------------------------------
__global__ __launch_bounds__(256)
void conv_silu_kernel(const float* __restrict__ xpre,
                      const float* __restrict__ conv_w,
                      const float* __restrict__ conv_b,
                      float* __restrict__ xb)
{
    int idx = blockIdx.x * blockDim.x + threadIdx.x;
    int c = idx % D_INNER;
    int l = (idx / D_INNER) % SEQLEN;
    int b = idx / (D_INNER * SEQLEN);
    const float* base = xpre + (size_t)b * SEQLEN * D_INNER + c;
    float w0 = conv_w[c*4+0], w1 = conv_w[c*4+1];
    float w2 = conv_w[c*4+2], w3 = conv_w[c*4+3];
    float acc = conv_b[c];
    if (l >= 3) acc += w0 * base[(l-3) * D_INNER];
    if (l >= 2) acc += w1 * base[(l-2) * D_INNER];
    if (l >= 1) acc += w2 * base[(l-1) * D_INNER];
    acc += w3 * base[l * D_INNER];
    xb[idx] = silu_f(acc);
}

// ---------------------------------------------------------------------------
// Chunked selective scan (see round-2 comments).
// ---------------------------------------------------------------------------
__global__ __launch_bounds__(256)
void scan_phase1(const float* __restrict__ dt,
                 const float* __restrict__ xdbl,
                 const float* __restrict__ xb,
                 const float* __restrict__ A_log,
                 float* __restrict__ Pbuf, float* __restrict__ hbuf)
{
    int bx = blockIdx.x;
    int dg = bx & 127;
    int c  = (bx >> 7) & (NCHUNK - 1);
    int b  = bx >> 11;
    int d0 = dg * CH;
    int t  = threadIdx.x;
    int s  = t & 15, ch = t >> 4;
    int d  = d0 + ch;
    int l0 = c * LC;

    __shared__ __align__(16) float dt_t[LC][CH];
    __shared__ __align__(16) float x_t[LC][CH];
    __shared__ __align__(16) float B_t[LC][D_STATE];
    {
        int row = t >> 2, c4 = (t & 3) * 4;
        size_t rbase = (size_t)(b * SEQLEN + l0 + row);
        *(float4*)&dt_t[row][c4] = *(const float4*)(dt   + rbase * D_INNER + d0 + c4);
        *(float4*)&x_t[row][c4]  = *(const float4*)(xb   + rbase * D_INNER + d0 + c4);
        *(float4*)&B_t[row][c4]  = *(const float4*)(xdbl + rbase * 96 + DT_RANK + c4);
    }
    float As = -__expf(A_log[d * D_STATE + s]);
    __syncthreads();

    float h = 0.0f, P = 1.0f;
    #pragma unroll
    for (int l = 0; l < LC; l++) {
        float dtv = dt_t[l][ch];
        float a = __expf(dtv * As);
        h = a * h + (dtv * x_t[l][ch]) * B_t[l][s];
        P *= a;
    }
    size_t idx = (((size_t)(b * NCHUNK + c)) * D_INNER + d) * D_STATE + s;
    Pbuf[idx] = P;
    hbuf[idx] = h;
}

__global__ __launch_bounds__(256)
void scan_carry(float* __restrict__ Pbuf, const float* __restrict__ hbuf)
{
    int t = blockIdx.x * blockDim.x + threadIdx.x;
    int s = t & 15;
    int d = (t >> 4) & (D_INNER - 1);
    int b = t >> 15;
    float h = 0.0f;
    #pragma unroll
    for (int c = 0; c < NCHUNK; c++) {
        size_t idx = (((size_t)(b * NCHUNK + c)) * D_INNER + d) * D_STATE + s;
        float Pc = Pbuf[idx];
        float hl = hbuf[idx];
        Pbuf[idx] = h;
        h = Pc * h + hl;
    }
}

__global__ __launch_bounds__(256)
void scan_phase2(const float* __restrict__ dt,
                 const float* __restrict__ xdbl,
                 const float* __restrict__ xb,
                 const float* __restrict__ A_log,
                 const float* __restrict__ Dvec,
                 const float* __restrict__ hinbuf,
                 float* __restrict__ zio)
{
    int bx = blockIdx.x;
    int dg = bx & 127;
    int c  = (bx >> 7) & (NCHUNK - 1);
    int b  = bx >> 11;
    int d0 = dg * CH;
    int t  = threadIdx.x;
    int s  = t & 15, ch = t >> 4;
    int d  = d0 + ch;
    int l0 = c * LC;

    __shared__ __align__(16) float dt_t[LC][CH];
    __shared__ __align__(16) float x_t[LC][CH];
    __shared__ __align__(16) float z_t[LC][CH];
    __shared__ __align__(16) float B_t[LC][D_STATE];
    __shared__ __align__(16) float C_t[LC][D_STATE];
    __shared__ __align__(16) float y_t[LC][CH];
    {
        int row = t >> 2, c4 = (t & 3) * 4;
        size_t rbase = (size_t)(b * SEQLEN + l0 + row);
        *(float4*)&dt_t[row][c4] = *(const float4*)(dt   + rbase * D_INNER + d0 + c4);
        *(float4*)&x_t[row][c4]  = *(const float4*)(xb   + rbase * D_INNER + d0 + c4);
        *(float4*)&z_t[row][c4]  = *(const float4*)(zio  + rbase * D_INNER + d0 + c4);
        *(float4*)&B_t[row][c4]  = *(const float4*)(xdbl + rbase * 96 + DT_RANK + c4);
        *(float4*)&C_t[row][c4]  = *(const float4*)(xdbl + rbase * 96 + DT_RANK + D_STATE + c4);
    }
    float As = -__expf(A_log[d * D_STATE + s]);
    float Dd = Dvec[d];
    size_t idx = (((size_t)(b * NCHUNK + c)) * D_INNER + d) * D_STATE + s;
    float h = hinbuf[idx];
    __syncthreads();

    #pragma unroll
    for (int l = 0; l < LC; l++) {
        float dtv = dt_t[l][ch];
        float xv  = x_t[l][ch];
        float a = __expf(dtv * As);
        h = a * h + (dtv * xv) * B_t[l][s];
        float p = h * C_t[l][s];
        p += __shfl_xor(p, 1);
        p += __shfl_xor(p, 2);
        p += __shfl_xor(p, 4);
        p += __shfl_xor(p, 8);
        if (s == 0) y_t[l][ch] = (p + xv * Dd) * z_t[l][ch];
    }
    __syncthreads();
    {
        int row = t >> 2, c4 = (t & 3) * 4;
        size_t rbase = (size_t)(b * SEQLEN + l0 + row);
        *(float4*)(zio + rbase * D_INNER + d0 + c4) = *(float4*)&y_t[row][c4];
    }
}

// ---------------------------------------------------------------------------
extern "C" void kernel_launch(void* const* d_in, const int* in_sizes, int n_in,
                              void* d_out, int out_size, void* d_ws, size_t ws_size,
                              hipStream_t stream)
{
    const float* x          = (const float*)d_in[0];
    const float* in_proj_w  = (const float*)d_in[1];
    const float* in_proj_b  = (const float*)d_in[2];
    const float* conv_w     = (const float*)d_in[3];
    const float* conv_b     = (const float*)d_in[4];
    const float* x_proj_w   = (const float*)d_in[5];
    const float* dt_proj_w  = (const float*)d_in[6];
    const float* dt_proj_b  = (const float*)d_in[7];
    const float* A_log      = (const float*)d_in[8];
    const float* Dv         = (const float*)d_in[9];
    const float* out_proj_w = (const float*)d_in[10];
    const float* out_proj_b = (const float*)d_in[11];
    float* out = (float*)d_out;

    float* ws   = (float*)d_ws;
    float* xpre = ws;
    float* xb   = ws + (size_t)M_TOTAL * D_INNER;
    float* zb   = ws + (size_t)2 * M_TOTAL * D_INNER;
    float* xdbl = ws + (size_t)3 * M_TOTAL * D_INNER;
    float* dt   = xpre;  // reuse: xpre dead after conv

    // Scan scratch lives in d_out (dead until final GEMM overwrites it).
    float* Pbuf = out;
    float* hbuf = out + (size_t)BATCH * NCHUNK * D_INNER * D_STATE;

    // 1) in_proj (f16 MFMA): xz = x @ in_proj_w^T + b ; split xpre / silu(z)
    {
        dim3 grid((2*D_INNER)/128, M_TOTAL/128);
        gemm_mfma<0><<<grid, 256, 0, stream>>>(
            x, D_MODEL, in_proj_w, D_MODEL, in_proj_b,
            xpre, zb, 2*D_INNER, D_MODEL);
    }
    // 2) causal depthwise conv + silu
    conv_silu_kernel<<<(BATCH*SEQLEN*D_INNER)/256, 256, 0, stream>>>(
        xpre, conv_w, conv_b, xb);
    // 3) x_proj (f32): xdbl = xb @ x_proj_w^T   (N = 96)
    {
        dim3 grid(96/32, M_TOTAL/64);
        gemm_nt<64,32,16,4,4,1><<<grid, 128, 0, stream>>>(
            xb, D_INNER, x_proj_w, D_INNER, nullptr,
            xdbl, M_TOTAL, 96, D_INNER);
    }
    // 4) dt_proj (f32): dt = softplus(xdbl[:, :64] @ dt_proj_w^T + b)
    {
        dim3 grid(D_INNER/64, M_TOTAL/64);
        gemm_nt<64,64,16,4,4,2><<<grid, 256, 0, stream>>>(
            xdbl, 96, dt_proj_w, DT_RANK, dt_proj_b,
            dt, M_TOTAL, D_INNER, DT_RANK);
    }
    // 5) chunked selective scan (+D skip, +z gate) — overwrites zb
    {
        int nblk = BATCH * NCHUNK * (D_INNER / CH);   // 4096
        scan_phase1<<<nblk, 256, 0, stream>>>(dt, xdbl, xb, A_log, Pbuf, hbuf);
        scan_carry<<<(BATCH*D_INNER*D_STATE)/256, 256, 0, stream>>>(Pbuf, hbuf);
        scan_phase2<<<nblk, 256, 0, stream>>>(dt, xdbl, xb, A_log, Dv, Pbuf, zb);
    }
    // 6) out_proj (f16 MFMA): out = ygated @ out_proj_w^T + b
    {
        dim3 grid(D_MODEL/128, M_TOTAL/128);
        gemm_mfma<3><<<grid, 256, 0, stream>>>(
            zb, D_INNER, out_proj_w, D_INNER, out_proj_b,
            out, nullptr, D_MODEL, D_INNER);
    }
}

// Round 6
// 361.776 us; speedup vs baseline: 3.9546x; 1.1925x over previous
//
#include <hip/hip_runtime.h>
#include <math.h>

#define D_STATE 16
#define D_CONV 4
#define DT_RANK 64
#define D_INNER 2048
#define D_MODEL 1024
#define BATCH 2
#define SEQLEN 1024
#define M_TOTAL (BATCH*SEQLEN)  // 2048

#define LC 64                    // scan chunk length
#define NCHUNK (SEQLEN/LC)       // 16
#define CH 16                    // channels per scan block

#define XKSPLIT 16
#define XKCHUNK (D_INNER/XKSPLIT)   // 128

typedef __fp16   h2s_t  __attribute__((ext_vector_type(2)));  // pkrtz result
typedef __fp16   h8s_t  __attribute__((ext_vector_type(8)));  // storage vec
typedef _Float16 half8  __attribute__((ext_vector_type(8)));  // MFMA operand
typedef float    floatx4 __attribute__((ext_vector_type(4)));

union HalfPack { h2s_t h2[4]; h8s_t h8; };

__device__ __forceinline__ float silu_f(float x) {
    return x / (1.0f + __expf(-x));
}
__device__ __forceinline__ float softplus_f(float x) {
    return fmaxf(x, 0.0f) + log1pf(__expf(-fabsf(x)));
}

__device__ __forceinline__ h8s_t pack8(const float4& v0, const float4& v1) {
    HalfPack p;
    p.h2[0] = __builtin_amdgcn_cvt_pkrtz(v0.x, v0.y);
    p.h2[1] = __builtin_amdgcn_cvt_pkrtz(v0.z, v0.w);
    p.h2[2] = __builtin_amdgcn_cvt_pkrtz(v1.x, v1.y);
    p.h2[3] = __builtin_amdgcn_cvt_pkrtz(v1.z, v1.w);
    return p.h8;
}

// ---------------------------------------------------------------------------
// f16-MFMA NT GEMM, f32 in/out, cast-on-stage (pkrtz -> __fp16 LDS tiles).
// C[m,n] = sum_k A[m*lda+k] * B[n*ldb+k]; f32 accumulate via MFMA.
// MODE 0: v=acc+bias[n]; n<D_INNER -> out0[m*D_INNER+n]=v else out1=silu(v)
// MODE 3: out0[m*N+n] = acc + bias[n]
// Tile 128x128x32, 256 threads (4 waves), each wave 64x64 via 4x4 MFMA tiles.
// LDS rows padded to 40 halfs (80B): frag reads land 2-way aliased (free).
// ---------------------------------------------------------------------------
template<int MODE>
__global__ __launch_bounds__(256)
void gemm_mfma(const float* __restrict__ A, int lda,
               const float* __restrict__ B, int ldb,
               const float* __restrict__ bias,
               float* __restrict__ out0, float* __restrict__ out1,
               int N, int K)
{
    constexpr int BM = 128, BN = 128, BK = 32;
    constexpr int LDH = 40;  // padded halfs per row
    __shared__ __fp16 As[BM * LDH];
    __shared__ __fp16 Bs[BN * LDH];

    const int tid  = threadIdx.x;
    const int bm   = blockIdx.y * BM;
    const int bn   = blockIdx.x * BN;
    const int wave = tid >> 6;
    const int lane = tid & 63;
    const int wm   = (wave >> 1) * 64;   // wave m-offset within tile
    const int wn   = (wave & 1) * 64;    // wave n-offset within tile
    const int fr   = lane & 15;          // frag row (A: m, B: n)
    const int fk   = (lane >> 4) * 8;    // frag k offset

    const int srow = tid >> 2;
    const int skc  = (tid & 3) * 8;

    floatx4 zero = {0.f, 0.f, 0.f, 0.f};
    floatx4 acc[4][4];
    #pragma unroll
    for (int i = 0; i < 4; i++)
        #pragma unroll
        for (int j = 0; j < 4; j++) acc[i][j] = zero;

    for (int kt = 0; kt < K; kt += BK) {
        #pragma unroll
        for (int hidx = 0; hidx < 2; hidx++) {
            int row = srow + hidx * 64;
            const float* ga = A + (size_t)(bm + row) * lda + kt + skc;
            *(h8s_t*)&As[row * LDH + skc] =
                pack8(*(const float4*)ga, *(const float4*)(ga + 4));
            const float* gb = B + (size_t)(bn + row) * ldb + kt + skc;
            *(h8s_t*)&Bs[row * LDH + skc] =
                pack8(*(const float4*)gb, *(const float4*)(gb + 4));
        }
        __syncthreads();

        half8 af[4], bf[4];
        #pragma unroll
        for (int i = 0; i < 4; i++)
            af[i] = *(half8*)&As[(wm + i*16 + fr) * LDH + fk];
        #pragma unroll
        for (int j = 0; j < 4; j++)
            bf[j] = *(half8*)&Bs[(wn + j*16 + fr) * LDH + fk];
        #pragma unroll
        for (int i = 0; i < 4; i++)
            #pragma unroll
            for (int j = 0; j < 4; j++)
                acc[i][j] = __builtin_amdgcn_mfma_f32_16x16x32_f16(
                    af[i], bf[j], acc[i][j], 0, 0, 0);
        __syncthreads();
    }

    // epilogue: C/D layout col=lane&15, row=(lane>>4)*4+reg
    const int rbase = (lane >> 4) * 4;
    #pragma unroll
    for (int i = 0; i < 4; i++) {
        #pragma unroll
        for (int j = 0; j < 4; j++) {
            int n = bn + wn + j*16 + fr;
            float bv = bias[n];
            #pragma unroll
            for (int r = 0; r < 4; r++) {
                int m = bm + wm + i*16 + rbase + r;
                float v = acc[i][j][r] + bv;
                if (MODE == 0) {
                    if (n < D_INNER) out0[(size_t)m * D_INNER + n] = v;
                    else             out1[(size_t)m * D_INNER + (n - D_INNER)] = silu_f(v);
                } else {
                    out0[(size_t)m * N + n] = v;
                }
            }
        }
    }
}

// ---------------------------------------------------------------------------
// x_proj split-K f16 MFMA: partials[p][m][96] = xb[m, kchunk_p] @ w^T.
// Block: 4 waves; M-tile 64 (16 rows/wave); N=96 (6 MFMA n-tiles);
// K-chunk 128 (4 K-steps of 32). Grid: (M/64) x XKSPLIT = 512 blocks.
// ---------------------------------------------------------------------------
__global__ __launch_bounds__(256)
void xproj_mfma(const float* __restrict__ A,      // xb, lda = D_INNER
                const float* __restrict__ B,      // x_proj_w (96 x D_INNER)
                float* __restrict__ partials)     // [XKSPLIT][M_TOTAL][96]
{
    constexpr int LDH = 40;
    __shared__ __fp16 As[64 * LDH];
    __shared__ __fp16 Bs[96 * LDH];

    const int tid = threadIdx.x;
    const int mt  = blockIdx.x * 64;
    const int p   = blockIdx.y;
    const int k0  = p * XKCHUNK;
    const int wave = tid >> 6;
    const int lane = tid & 63;
    const int fr = lane & 15;
    const int fk = (lane >> 4) * 8;

    floatx4 zero = {0.f, 0.f, 0.f, 0.f};
    floatx4 acc[6];
    #pragma unroll
    for (int j = 0; j < 6; j++) acc[j] = zero;

    for (int kt = 0; kt < XKCHUNK; kt += 32) {
        {   // stage A: 64 rows x 4 chunks = 256, one per thread
            int row = tid >> 2, kc = (tid & 3) * 8;
            const float* ga = A + (size_t)(mt + row) * D_INNER + k0 + kt + kc;
            *(h8s_t*)&As[row * LDH + kc] =
                pack8(*(const float4*)ga, *(const float4*)(ga + 4));
        }
        {   // stage B: 96 rows x 4 chunks = 384
            int row = tid >> 2, kc = (tid & 3) * 8;
            const float* gb = B + (size_t)row * D_INNER + k0 + kt + kc;
            *(h8s_t*)&Bs[row * LDH + kc] =
                pack8(*(const float4*)gb, *(const float4*)(gb + 4));
            if (tid < 128) {
                int c2 = tid + 256;
                int row2 = c2 >> 2, kc2 = (c2 & 3) * 8;
                const float* gb2 = B + (size_t)row2 * D_INNER + k0 + kt + kc2;
                *(h8s_t*)&Bs[row2 * LDH + kc2] =
                    pack8(*(const float4*)gb2, *(const float4*)(gb2 + 4));
            }
        }
        __syncthreads();

        half8 af = *(half8*)&As[(wave * 16 + fr) * LDH + fk];
        #pragma unroll
        for (int j = 0; j < 6; j++) {
            half8 bf = *(half8*)&Bs[(j * 16 + fr) * LDH + fk];
            acc[j] = __builtin_amdgcn_mfma_f32_16x16x32_f16(af, bf, acc[j], 0, 0, 0);
        }
        __syncthreads();
    }

    const int rbase = (lane >> 4) * 4;
    float* outp = partials + ((size_t)p * M_TOTAL + mt + wave * 16) * 96;
    #pragma unroll
    for (int j = 0; j < 6; j++) {
        int n = j * 16 + fr;
        #pragma unroll
        for (int r = 0; r < 4; r++)
            outp[(size_t)(rbase + r) * 96 + n] = acc[j][r];
    }
}

__global__ __launch_bounds__(256)
void xproj_reduce(const float* __restrict__ partials, float* __restrict__ xdbl)
{
    int i = blockIdx.x * 256 + threadIdx.x;   // over M_TOTAL*96
    float s = 0.0f;
    #pragma unroll
    for (int p = 0; p < XKSPLIT; p++)
        s += partials[(size_t)p * M_TOTAL * 96 + i];
    xdbl[i] = s;
}

// ---------------------------------------------------------------------------
// f32 vector-ALU NT GEMM (kept for dt_proj).
// MODE 2: out0[m*N+n] = softplus(acc + bias[n])
// ---------------------------------------------------------------------------
template<int BM, int BN, int BK, int TM, int TN, int MODE>
__global__ __launch_bounds__((BM/TM)*(BN/TN))
void gemm_nt(const float* __restrict__ A, int lda,
             const float* __restrict__ B, int ldb,
             const float* __restrict__ bias,
             float* __restrict__ out0,
             int M, int N, int K)
{
    constexpr int THREADS = (BM/TM)*(BN/TN);
    __shared__ float As[BK][BM+4];
    __shared__ float Bs[BK][BN+4];
    const int tid = threadIdx.x;
    const int bm = blockIdx.y * BM;
    const int bn = blockIdx.x * BN;
    const int tx = tid % (BN/TN);
    const int ty = tid / (BN/TN);

    float acc[TM][TN];
    #pragma unroll
    for (int i = 0; i < TM; i++)
        #pragma unroll
        for (int j = 0; j < TN; j++) acc[i][j] = 0.0f;

    constexpr int F4_PER_ROW = BK / 4;
    constexpr int A_ROWS_PER_ITER = THREADS / F4_PER_ROW;
    constexpr int B_ROWS_PER_ITER = THREADS / F4_PER_ROW;

    for (int kt = 0; kt < K; kt += BK) {
        #pragma unroll
        for (int r = 0; r < BM; r += A_ROWS_PER_ITER) {
            int row = r + tid / F4_PER_ROW;
            int kc  = (tid % F4_PER_ROW) * 4;
            float4 v = *(const float4*)(A + (size_t)(bm + row) * lda + kt + kc);
            As[kc+0][row] = v.x; As[kc+1][row] = v.y;
            As[kc+2][row] = v.z; As[kc+3][row] = v.w;
        }
        #pragma unroll
        for (int r = 0; r < BN; r += B_ROWS_PER_ITER) {
            int row = r + tid / F4_PER_ROW;
            int kc  = (tid % F4_PER_ROW) * 4;
            float4 v = *(const float4*)(B + (size_t)(bn + row) * ldb + kt + kc);
            Bs[kc+0][row] = v.x; Bs[kc+1][row] = v.y;
            Bs[kc+2][row] = v.z; Bs[kc+3][row] = v.w;
        }
        __syncthreads();
        #pragma unroll
        for (int k = 0; k < BK; k++) {
            float ra[TM], rb[TN];
            #pragma unroll
            for (int i = 0; i < TM; i++) ra[i] = As[k][ty*TM + i];
            #pragma unroll
            for (int j = 0; j < TN; j++) rb[j] = Bs[k][tx*TN + j];
            #pragma unroll
            for (int i = 0; i < TM; i++)
                #pragma unroll
                for (int j = 0; j < TN; j++) acc[i][j] += ra[i] * rb[j];
        }
        __syncthreads();
    }

    #pragma unroll
    for (int i = 0; i < TM; i++) {
        int m = bm + ty*TM + i;
        #pragma unroll
        for (int j = 0; j < TN; j++) {
            int n = bn + tx*TN + j;
            float v = acc[i][j];
            if (MODE == 1) out0[(size_t)m * N + n] = v;
            else           out0[(size_t)m * N + n] = softplus_f(v + bias[n]);
        }
    }
}

// ---------------------------------------------------------------------------
// Causal depthwise conv (4 taps, left pad 3) + SiLU.  Layout (b, l, c).
// ---------------------------------------------------------------------------
__global__ __launch_bounds__(256)
void conv_silu_kernel(const float* __restrict__ xpre,
                      const float* __restrict__ conv_w,
                      const float* __restrict__ conv_b,
                      float* __restrict__ xb)
{
    int idx = blockIdx.x * blockDim.x + threadIdx.x;
    int c = idx % D_INNER;
    int l = (idx / D_INNER) % SEQLEN;
    int b = idx / (D_INNER * SEQLEN);
    const float* base = xpre + (size_t)b * SEQLEN * D_INNER + c;
    float w0 = conv_w[c*4+0], w1 = conv_w[c*4+1];
    float w2 = conv_w[c*4+2], w3 = conv_w[c*4+3];
    float acc = conv_b[c];
    if (l >= 3) acc += w0 * base[(l-3) * D_INNER];
    if (l >= 2) acc += w1 * base[(l-2) * D_INNER];
    if (l >= 1) acc += w2 * base[(l-1) * D_INNER];
    acc += w3 * base[l * D_INNER];
    xb[idx] = silu_f(acc);
}

// ---------------------------------------------------------------------------
// Chunked selective scan (see round-2 comments).
// ---------------------------------------------------------------------------
__global__ __launch_bounds__(256)
void scan_phase1(const float* __restrict__ dt,
                 const float* __restrict__ xdbl,
                 const float* __restrict__ xb,
                 const float* __restrict__ A_log,
                 float* __restrict__ Pbuf, float* __restrict__ hbuf)
{
    int bx = blockIdx.x;
    int dg = bx & 127;
    int c  = (bx >> 7) & (NCHUNK - 1);
    int b  = bx >> 11;
    int d0 = dg * CH;
    int t  = threadIdx.x;
    int s  = t & 15, ch = t >> 4;
    int d  = d0 + ch;
    int l0 = c * LC;

    __shared__ __align__(16) float dt_t[LC][CH];
    __shared__ __align__(16) float x_t[LC][CH];
    __shared__ __align__(16) float B_t[LC][D_STATE];
    {
        int row = t >> 2, c4 = (t & 3) * 4;
        size_t rbase = (size_t)(b * SEQLEN + l0 + row);
        *(float4*)&dt_t[row][c4] = *(const float4*)(dt   + rbase * D_INNER + d0 + c4);
        *(float4*)&x_t[row][c4]  = *(const float4*)(xb   + rbase * D_INNER + d0 + c4);
        *(float4*)&B_t[row][c4]  = *(const float4*)(xdbl + rbase * 96 + DT_RANK + c4);
    }
    float As = -__expf(A_log[d * D_STATE + s]);
    __syncthreads();

    float h = 0.0f, P = 1.0f;
    #pragma unroll
    for (int l = 0; l < LC; l++) {
        float dtv = dt_t[l][ch];
        float a = __expf(dtv * As);
        h = a * h + (dtv * x_t[l][ch]) * B_t[l][s];
        P *= a;
    }
    size_t idx = (((size_t)(b * NCHUNK + c)) * D_INNER + d) * D_STATE + s;
    Pbuf[idx] = P;
    hbuf[idx] = h;
}

__global__ __launch_bounds__(256)
void scan_carry(float* __restrict__ Pbuf, const float* __restrict__ hbuf)
{
    int t = blockIdx.x * blockDim.x + threadIdx.x;
    int s = t & 15;
    int d = (t >> 4) & (D_INNER - 1);
    int b = t >> 15;
    float h = 0.0f;
    #pragma unroll
    for (int c = 0; c < NCHUNK; c++) {
        size_t idx = (((size_t)(b * NCHUNK + c)) * D_INNER + d) * D_STATE + s;
        float Pc = Pbuf[idx];
        float hl = hbuf[idx];
        Pbuf[idx] = h;
        h = Pc * h + hl;
    }
}

__global__ __launch_bounds__(256)
void scan_phase2(const float* __restrict__ dt,
                 const float* __restrict__ xdbl,
                 const float* __restrict__ xb,
                 const float* __restrict__ A_log,
                 const float* __restrict__ Dvec,
                 const float* __restrict__ hinbuf,
                 float* __restrict__ zio)
{
    int bx = blockIdx.x;
    int dg = bx & 127;
    int c  = (bx >> 7) & (NCHUNK - 1);
    int b  = bx >> 11;
    int d0 = dg * CH;
    int t  = threadIdx.x;
    int s  = t & 15, ch = t >> 4;
    int d  = d0 + ch;
    int l0 = c * LC;

    __shared__ __align__(16) float dt_t[LC][CH];
    __shared__ __align__(16) float x_t[LC][CH];
    __shared__ __align__(16) float z_t[LC][CH];
    __shared__ __align__(16) float B_t[LC][D_STATE];
    __shared__ __align__(16) float C_t[LC][D_STATE];
    __shared__ __align__(16) float y_t[LC][CH];
    {
        int row = t >> 2, c4 = (t & 3) * 4;
        size_t rbase = (size_t)(b * SEQLEN + l0 + row);
        *(float4*)&dt_t[row][c4] = *(const float4*)(dt   + rbase * D_INNER + d0 + c4);
        *(float4*)&x_t[row][c4]  = *(const float4*)(xb   + rbase * D_INNER + d0 + c4);
        *(float4*)&z_t[row][c4]  = *(const float4*)(zio  + rbase * D_INNER + d0 + c4);
        *(float4*)&B_t[row][c4]  = *(const float4*)(xdbl + rbase * 96 + DT_RANK + c4);
        *(float4*)&C_t[row][c4]  = *(const float4*)(xdbl + rbase * 96 + DT_RANK + D_STATE + c4);
    }
    float As = -__expf(A_log[d * D_STATE + s]);
    float Dd = Dvec[d];
    size_t idx = (((size_t)(b * NCHUNK + c)) * D_INNER + d) * D_STATE + s;
    float h = hinbuf[idx];
    __syncthreads();

    #pragma unroll
    for (int l = 0; l < LC; l++) {
        float dtv = dt_t[l][ch];
        float xv  = x_t[l][ch];
        float a = __expf(dtv * As);
        h = a * h + (dtv * xv) * B_t[l][s];
        float p = h * C_t[l][s];
        p += __shfl_xor(p, 1);
        p += __shfl_xor(p, 2);
        p += __shfl_xor(p, 4);
        p += __shfl_xor(p, 8);
        if (s == 0) y_t[l][ch] = (p + xv * Dd) * z_t[l][ch];
    }
    __syncthreads();
    {
        int row = t >> 2, c4 = (t & 3) * 4;
        size_t rbase = (size_t)(b * SEQLEN + l0 + row);
        *(float4*)(zio + rbase * D_INNER + d0 + c4) = *(float4*)&y_t[row][c4];
    }
}

// ---------------------------------------------------------------------------
extern "C" void kernel_launch(void* const* d_in, const int* in_sizes, int n_in,
                              void* d_out, int out_size, void* d_ws, size_t ws_size,
                              hipStream_t stream)
{
    const float* x          = (const float*)d_in[0];
    const float* in_proj_w  = (const float*)d_in[1];
    const float* in_proj_b  = (const float*)d_in[2];
    const float* conv_w     = (const float*)d_in[3];
    const float* conv_b     = (const float*)d_in[4];
    const float* x_proj_w   = (const float*)d_in[5];
    const float* dt_proj_w  = (const float*)d_in[6];
    const float* dt_proj_b  = (const float*)d_in[7];
    const float* A_log      = (const float*)d_in[8];
    const float* Dv         = (const float*)d_in[9];
    const float* out_proj_w = (const float*)d_in[10];
    const float* out_proj_b = (const float*)d_in[11];
    float* out = (float*)d_out;

    float* ws   = (float*)d_ws;
    float* xpre = ws;
    float* xb   = ws + (size_t)M_TOTAL * D_INNER;
    float* zb   = ws + (size_t)2 * M_TOTAL * D_INNER;
    float* xdbl = ws + (size_t)3 * M_TOTAL * D_INNER;
    float* dt   = xpre;        // reuse: xpre dead after conv
    float* xpart = xpre;       // x_proj split-K partials (12.6 MB <= 16.8 MB),
                               // dead again once xproj_reduce finishes

    // Scan scratch lives in d_out (dead until final GEMM overwrites it).
    float* Pbuf = out;
    float* hbuf = out + (size_t)BATCH * NCHUNK * D_INNER * D_STATE;

    // 1) in_proj (f16 MFMA): xz = x @ in_proj_w^T + b ; split xpre / silu(z)
    {
        dim3 grid((2*D_INNER)/128, M_TOTAL/128);
        gemm_mfma<0><<<grid, 256, 0, stream>>>(
            x, D_MODEL, in_proj_w, D_MODEL, in_proj_b,
            xpre, zb, 2*D_INNER, D_MODEL);
    }
    // 2) causal depthwise conv + silu
    conv_silu_kernel<<<(BATCH*SEQLEN*D_INNER)/256, 256, 0, stream>>>(
        xpre, conv_w, conv_b, xb);
    // 3) x_proj (split-K f16 MFMA): xdbl = xb @ x_proj_w^T   (N = 96)
    {
        dim3 grid(M_TOTAL/64, XKSPLIT);
        xproj_mfma<<<grid, 256, 0, stream>>>(xb, x_proj_w, xpart);
        xproj_reduce<<<(M_TOTAL*96)/256, 256, 0, stream>>>(xpart, xdbl);
    }
    // 4) dt_proj (f32): dt = softplus(xdbl[:, :64] @ dt_proj_w^T + b)
    {
        dim3 grid(D_INNER/64, M_TOTAL/64);
        gemm_nt<64,64,16,4,4,2><<<grid, 256, 0, stream>>>(
            xdbl, 96, dt_proj_w, DT_RANK, dt_proj_b,
            dt, M_TOTAL, D_INNER, DT_RANK);
    }
    // 5) chunked selective scan (+D skip, +z gate) — overwrites zb
    {
        int nblk = BATCH * NCHUNK * (D_INNER / CH);   // 4096
        scan_phase1<<<nblk, 256, 0, stream>>>(dt, xdbl, xb, A_log, Pbuf, hbuf);
        scan_carry<<<(BATCH*D_INNER*D_STATE)/256, 256, 0, stream>>>(Pbuf, hbuf);
        scan_phase2<<<nblk, 256, 0, stream>>>(dt, xdbl, xb, A_log, Dv, Pbuf, zb);
    }
    // 6) out_proj (f16 MFMA): out = ygated @ out_proj_w^T + b
    {
        dim3 grid(D_MODEL/128, M_TOTAL/128);
        gemm_mfma<3><<<grid, 256, 0, stream>>>(
            zb, D_INNER, out_proj_w, D_INNER, out_proj_b,
            out, nullptr, D_MODEL, D_INNER);
    }
}

// Round 7
// 313.287 us; speedup vs baseline: 4.5667x; 1.1548x over previous
//
#include <hip/hip_runtime.h>
#include <math.h>

#define D_STATE 16
#define D_CONV 4
#define DT_RANK 64
#define D_INNER 2048
#define D_MODEL 1024
#define BATCH 2
#define SEQLEN 1024
#define M_TOTAL (BATCH*SEQLEN)  // 2048

#define LC 64                    // scan chunk length
#define NCHUNK (SEQLEN/LC)       // 16
#define CHB 64                   // channels per scan block (4 s-lanes each)

#define XKSPLIT 16
#define XKCHUNK (D_INNER/XKSPLIT)   // 128

typedef __fp16   h2s_t  __attribute__((ext_vector_type(2)));  // pkrtz result
typedef __fp16   h8s_t  __attribute__((ext_vector_type(8)));  // storage vec
typedef _Float16 half8  __attribute__((ext_vector_type(8)));  // MFMA operand
typedef float    floatx4 __attribute__((ext_vector_type(4)));

union HalfPack { h2s_t h2[4]; h8s_t h8; };

__device__ __forceinline__ float silu_f(float x) {
    return x / (1.0f + __expf(-x));
}
__device__ __forceinline__ float softplus_f(float x) {
    return fmaxf(x, 0.0f) + log1pf(__expf(-fabsf(x)));
}

__device__ __forceinline__ h8s_t pack8(const float4& v0, const float4& v1) {
    HalfPack p;
    p.h2[0] = __builtin_amdgcn_cvt_pkrtz(v0.x, v0.y);
    p.h2[1] = __builtin_amdgcn_cvt_pkrtz(v0.z, v0.w);
    p.h2[2] = __builtin_amdgcn_cvt_pkrtz(v1.x, v1.y);
    p.h2[3] = __builtin_amdgcn_cvt_pkrtz(v1.z, v1.w);
    return p.h8;
}

// ---------------------------------------------------------------------------
// f16-MFMA NT GEMM, f32 in/out, cast-on-stage (pkrtz -> __fp16 LDS tiles).
// MODE 0: v=acc+bias[n]; n<D_INNER -> out0[m*D_INNER+n]=v else out1=silu(v)
// MODE 3: out0[m*N+n] = acc + bias[n]
// ---------------------------------------------------------------------------
template<int MODE>
__global__ __launch_bounds__(256)
void gemm_mfma(const float* __restrict__ A, int lda,
               const float* __restrict__ B, int ldb,
               const float* __restrict__ bias,
               float* __restrict__ out0, float* __restrict__ out1,
               int N, int K)
{
    constexpr int BM = 128, BN = 128, BK = 32;
    constexpr int LDH = 40;  // padded halfs per row
    __shared__ __fp16 As[BM * LDH];
    __shared__ __fp16 Bs[BN * LDH];

    const int tid  = threadIdx.x;
    const int bm   = blockIdx.y * BM;
    const int bn   = blockIdx.x * BN;
    const int wave = tid >> 6;
    const int lane = tid & 63;
    const int wm   = (wave >> 1) * 64;
    const int wn   = (wave & 1) * 64;
    const int fr   = lane & 15;
    const int fk   = (lane >> 4) * 8;

    const int srow = tid >> 2;
    const int skc  = (tid & 3) * 8;

    floatx4 zero = {0.f, 0.f, 0.f, 0.f};
    floatx4 acc[4][4];
    #pragma unroll
    for (int i = 0; i < 4; i++)
        #pragma unroll
        for (int j = 0; j < 4; j++) acc[i][j] = zero;

    for (int kt = 0; kt < K; kt += BK) {
        #pragma unroll
        for (int hidx = 0; hidx < 2; hidx++) {
            int row = srow + hidx * 64;
            const float* ga = A + (size_t)(bm + row) * lda + kt + skc;
            *(h8s_t*)&As[row * LDH + skc] =
                pack8(*(const float4*)ga, *(const float4*)(ga + 4));
            const float* gb = B + (size_t)(bn + row) * ldb + kt + skc;
            *(h8s_t*)&Bs[row * LDH + skc] =
                pack8(*(const float4*)gb, *(const float4*)(gb + 4));
        }
        __syncthreads();

        half8 af[4], bf[4];
        #pragma unroll
        for (int i = 0; i < 4; i++)
            af[i] = *(half8*)&As[(wm + i*16 + fr) * LDH + fk];
        #pragma unroll
        for (int j = 0; j < 4; j++)
            bf[j] = *(half8*)&Bs[(wn + j*16 + fr) * LDH + fk];
        #pragma unroll
        for (int i = 0; i < 4; i++)
            #pragma unroll
            for (int j = 0; j < 4; j++)
                acc[i][j] = __builtin_amdgcn_mfma_f32_16x16x32_f16(
                    af[i], bf[j], acc[i][j], 0, 0, 0);
        __syncthreads();
    }

    const int rbase = (lane >> 4) * 4;
    #pragma unroll
    for (int i = 0; i < 4; i++) {
        #pragma unroll
        for (int j = 0; j < 4; j++) {
            int n = bn + wn + j*16 + fr;
            float bv = bias[n];
            #pragma unroll
            for (int r = 0; r < 4; r++) {
                int m = bm + wm + i*16 + rbase + r;
                float v = acc[i][j][r] + bv;
                if (MODE == 0) {
                    if (n < D_INNER) out0[(size_t)m * D_INNER + n] = v;
                    else             out1[(size_t)m * D_INNER + (n - D_INNER)] = silu_f(v);
                } else {
                    out0[(size_t)m * N + n] = v;
                }
            }
        }
    }
}

// ---------------------------------------------------------------------------
// x_proj split-K f16 MFMA (see round-5 comments).
// ---------------------------------------------------------------------------
__global__ __launch_bounds__(256)
void xproj_mfma(const float* __restrict__ A,
                const float* __restrict__ B,
                float* __restrict__ partials)
{
    constexpr int LDH = 40;
    __shared__ __fp16 As[64 * LDH];
    __shared__ __fp16 Bs[96 * LDH];

    const int tid = threadIdx.x;
    const int mt  = blockIdx.x * 64;
    const int p   = blockIdx.y;
    const int k0  = p * XKCHUNK;
    const int wave = tid >> 6;
    const int lane = tid & 63;
    const int fr = lane & 15;
    const int fk = (lane >> 4) * 8;

    floatx4 zero = {0.f, 0.f, 0.f, 0.f};
    floatx4 acc[6];
    #pragma unroll
    for (int j = 0; j < 6; j++) acc[j] = zero;

    for (int kt = 0; kt < XKCHUNK; kt += 32) {
        {
            int row = tid >> 2, kc = (tid & 3) * 8;
            const float* ga = A + (size_t)(mt + row) * D_INNER + k0 + kt + kc;
            *(h8s_t*)&As[row * LDH + kc] =
                pack8(*(const float4*)ga, *(const float4*)(ga + 4));
        }
        {
            int row = tid >> 2, kc = (tid & 3) * 8;
            const float* gb = B + (size_t)row * D_INNER + k0 + kt + kc;
            *(h8s_t*)&Bs[row * LDH + kc] =
                pack8(*(const float4*)gb, *(const float4*)(gb + 4));
            if (tid < 128) {
                int c2 = tid + 256;
                int row2 = c2 >> 2, kc2 = (c2 & 3) * 8;
                const float* gb2 = B + (size_t)row2 * D_INNER + k0 + kt + kc2;
                *(h8s_t*)&Bs[row2 * LDH + kc2] =
                    pack8(*(const float4*)gb2, *(const float4*)(gb2 + 4));
            }
        }
        __syncthreads();

        half8 af = *(half8*)&As[(wave * 16 + fr) * LDH + fk];
        #pragma unroll
        for (int j = 0; j < 6; j++) {
            half8 bf = *(half8*)&Bs[(j * 16 + fr) * LDH + fk];
            acc[j] = __builtin_amdgcn_mfma_f32_16x16x32_f16(af, bf, acc[j], 0, 0, 0);
        }
        __syncthreads();
    }

    const int rbase = (lane >> 4) * 4;
    float* outp = partials + ((size_t)p * M_TOTAL + mt + wave * 16) * 96;
    #pragma unroll
    for (int j = 0; j < 6; j++) {
        int n = j * 16 + fr;
        #pragma unroll
        for (int r = 0; r < 4; r++)
            outp[(size_t)(rbase + r) * 96 + n] = acc[j][r];
    }
}

__global__ __launch_bounds__(256)
void xproj_reduce(const float* __restrict__ partials, float* __restrict__ xdbl)
{
    int i = blockIdx.x * 256 + threadIdx.x;
    float s = 0.0f;
    #pragma unroll
    for (int p = 0; p < XKSPLIT; p++)
        s += partials[(size_t)p * M_TOTAL * 96 + i];
    xdbl[i] = s;
}

// ---------------------------------------------------------------------------
// f32 vector-ALU NT GEMM (dt_proj). MODE 2: softplus(acc + bias[n])
// ---------------------------------------------------------------------------
template<int BM, int BN, int BK, int TM, int TN, int MODE>
__global__ __launch_bounds__((BM/TM)*(BN/TN))
void gemm_nt(const float* __restrict__ A, int lda,
             const float* __restrict__ B, int ldb,
             const float* __restrict__ bias,
             float* __restrict__ out0,
             int M, int N, int K)
{
    constexpr int THREADS = (BM/TM)*(BN/TN);
    __shared__ float As[BK][BM+4];
    __shared__ float Bs[BK][BN+4];
    const int tid = threadIdx.x;
    const int bm = blockIdx.y * BM;
    const int bn = blockIdx.x * BN;
    const int tx = tid % (BN/TN);
    const int ty = tid / (BN/TN);

    float acc[TM][TN];
    #pragma unroll
    for (int i = 0; i < TM; i++)
        #pragma unroll
        for (int j = 0; j < TN; j++) acc[i][j] = 0.0f;

    constexpr int F4_PER_ROW = BK / 4;
    constexpr int A_ROWS_PER_ITER = THREADS / F4_PER_ROW;
    constexpr int B_ROWS_PER_ITER = THREADS / F4_PER_ROW;

    for (int kt = 0; kt < K; kt += BK) {
        #pragma unroll
        for (int r = 0; r < BM; r += A_ROWS_PER_ITER) {
            int row = r + tid / F4_PER_ROW;
            int kc  = (tid % F4_PER_ROW) * 4;
            float4 v = *(const float4*)(A + (size_t)(bm + row) * lda + kt + kc);
            As[kc+0][row] = v.x; As[kc+1][row] = v.y;
            As[kc+2][row] = v.z; As[kc+3][row] = v.w;
        }
        #pragma unroll
        for (int r = 0; r < BN; r += B_ROWS_PER_ITER) {
            int row = r + tid / F4_PER_ROW;
            int kc  = (tid % F4_PER_ROW) * 4;
            float4 v = *(const float4*)(B + (size_t)(bn + row) * ldb + kt + kc);
            Bs[kc+0][row] = v.x; Bs[kc+1][row] = v.y;
            Bs[kc+2][row] = v.z; Bs[kc+3][row] = v.w;
        }
        __syncthreads();
        #pragma unroll
        for (int k = 0; k < BK; k++) {
            float ra[TM], rb[TN];
            #pragma unroll
            for (int i = 0; i < TM; i++) ra[i] = As[k][ty*TM + i];
            #pragma unroll
            for (int j = 0; j < TN; j++) rb[j] = Bs[k][tx*TN + j];
            #pragma unroll
            for (int i = 0; i < TM; i++)
                #pragma unroll
                for (int j = 0; j < TN; j++) acc[i][j] += ra[i] * rb[j];
        }
        __syncthreads();
    }

    #pragma unroll
    for (int i = 0; i < TM; i++) {
        int m = bm + ty*TM + i;
        #pragma unroll
        for (int j = 0; j < TN; j++) {
            int n = bn + tx*TN + j;
            float v = acc[i][j];
            if (MODE == 1) out0[(size_t)m * N + n] = v;
            else           out0[(size_t)m * N + n] = softplus_f(v + bias[n]);
        }
    }
}

// ---------------------------------------------------------------------------
// Causal depthwise conv (4 taps, left pad 3) + SiLU.  Layout (b, l, c).
// ---------------------------------------------------------------------------
__global__ __launch_bounds__(256)
void conv_silu_kernel(const float* __restrict__ xpre,
                      const float* __restrict__ conv_w,
                      const float* __restrict__ conv_b,
                      float* __restrict__ xb)
{
    int idx = blockIdx.x * blockDim.x + threadIdx.x;
    int c = idx % D_INNER;
    int l = (idx / D_INNER) % SEQLEN;
    int b = idx / (D_INNER * SEQLEN);
    const float* base = xpre + (size_t)b * SEQLEN * D_INNER + c;
    float w0 = conv_w[c*4+0], w1 = conv_w[c*4+1];
    float w2 = conv_w[c*4+2], w3 = conv_w[c*4+3];
    float acc = conv_b[c];
    if (l >= 3) acc += w0 * base[(l-3) * D_INNER];
    if (l >= 2) acc += w1 * base[(l-2) * D_INNER];
    if (l >= 1) acc += w2 * base[(l-1) * D_INNER];
    acc += w3 * base[l * D_INNER];
    xb[idx] = silu_f(acc);
}

// ---------------------------------------------------------------------------
// Chunked selective scan, state-quad threads (4 states/thread, 4 lanes/chan).
// Block covers CHB=64 channels of one chunk.  B/C fragments read as b128
// (16-fold wave broadcast); reduce over 4 lanes = 2 quad_perm shuffles.
// ---------------------------------------------------------------------------
__global__ __launch_bounds__(256)
void scan_phase1(const float* __restrict__ dt,
                 const float* __restrict__ xdbl,
                 const float* __restrict__ xb,
                 const float* __restrict__ A_log,
                 float* __restrict__ Pbuf, float* __restrict__ hbuf)
{
    int bx = blockIdx.x;
    int dg = bx & 31;                  // D_INNER/CHB = 32 groups
    int c  = (bx >> 5) & (NCHUNK - 1);
    int b  = bx >> 9;
    int d0 = dg * CHB;
    int t  = threadIdx.x;
    int s0 = (t & 3) * 4;
    int ch = t >> 2;
    int d  = d0 + ch;
    int l0 = c * LC;

    __shared__ __align__(16) float dt_t[LC][CHB];
    __shared__ __align__(16) float x_t[LC][CHB];
    __shared__ __align__(16) float B_t[LC][D_STATE];
    {
        int c4 = (t & 15) * 4;
        #pragma unroll
        for (int r = 0; r < 4; r++) {
            int row = (t >> 4) + r * 16;
            size_t g = (size_t)(b * SEQLEN + l0 + row) * D_INNER + d0 + c4;
            *(float4*)&dt_t[row][c4] = *(const float4*)(dt + g);
            *(float4*)&x_t[row][c4]  = *(const float4*)(xb + g);
        }
        int brow = t >> 2, bc4 = (t & 3) * 4;
        *(float4*)&B_t[brow][bc4] =
            *(const float4*)(xdbl + (size_t)(b*SEQLEN + l0 + brow)*96 + DT_RANK + bc4);
    }
    float4 Al = *(const float4*)(A_log + d * D_STATE + s0);
    float As0 = -__expf(Al.x), As1 = -__expf(Al.y);
    float As2 = -__expf(Al.z), As3 = -__expf(Al.w);
    __syncthreads();

    float h0=0,h1=0,h2=0,h3=0, P0=1,P1=1,P2=1,P3=1;
    #pragma unroll 4
    for (int l = 0; l < LC; l++) {
        float dtv = dt_t[l][ch];
        float dx  = dtv * x_t[l][ch];
        float4 Bv = *(float4*)&B_t[l][s0];
        float a0 = __expf(dtv*As0), a1 = __expf(dtv*As1);
        float a2 = __expf(dtv*As2), a3 = __expf(dtv*As3);
        h0 = a0*h0 + dx*Bv.x;  P0 *= a0;
        h1 = a1*h1 + dx*Bv.y;  P1 *= a1;
        h2 = a2*h2 + dx*Bv.z;  P2 *= a2;
        h3 = a3*h3 + dx*Bv.w;  P3 *= a3;
    }
    size_t idx = (((size_t)(b * NCHUNK + c)) * D_INNER + d) * D_STATE + s0;
    float4 Pv = {P0,P1,P2,P3}, hv = {h0,h1,h2,h3};
    *(float4*)&Pbuf[idx] = Pv;
    *(float4*)&hbuf[idx] = hv;
}

__global__ __launch_bounds__(256)
void scan_carry(float* __restrict__ Pbuf, const float* __restrict__ hbuf)
{
    int t = blockIdx.x * 256 + threadIdx.x;   // 0 .. B*D_INNER*4
    int s0 = (t & 3) * 4;
    int bd = t >> 2;
    int d = bd & (D_INNER - 1);
    int b = bd >> 11;
    float4 h = {0,0,0,0};
    #pragma unroll
    for (int c = 0; c < NCHUNK; c++) {
        size_t idx = (((size_t)(b * NCHUNK + c)) * D_INNER + d) * D_STATE + s0;
        float4 Pc = *(float4*)&Pbuf[idx];
        float4 hl = *(const float4*)&hbuf[idx];
        *(float4*)&Pbuf[idx] = h;
        h.x = Pc.x*h.x + hl.x;  h.y = Pc.y*h.y + hl.y;
        h.z = Pc.z*h.z + hl.z;  h.w = Pc.w*h.w + hl.w;
    }
}

__global__ __launch_bounds__(256)
void scan_phase2(const float* __restrict__ dt,
                 const float* __restrict__ xdbl,
                 const float* __restrict__ xb,
                 const float* __restrict__ A_log,
                 const float* __restrict__ Dvec,
                 const float* __restrict__ hinbuf,
                 float* __restrict__ zio)
{
    int bx = blockIdx.x;
    int dg = bx & 31;
    int c  = (bx >> 5) & (NCHUNK - 1);
    int b  = bx >> 9;
    int d0 = dg * CHB;
    int t  = threadIdx.x;
    int s0 = (t & 3) * 4;
    int ch = t >> 2;
    int d  = d0 + ch;
    int l0 = c * LC;

    __shared__ __align__(16) float dt_t[LC][CHB];
    __shared__ __align__(16) float x_t[LC][CHB];
    __shared__ __align__(16) float B_t[LC][D_STATE];
    __shared__ __align__(16) float C_t[LC][D_STATE];
    __shared__ __align__(16) float y_t[LC][CHB];
    {
        int c4 = (t & 15) * 4;
        #pragma unroll
        for (int r = 0; r < 4; r++) {
            int row = (t >> 4) + r * 16;
            size_t g = (size_t)(b * SEQLEN + l0 + row) * D_INNER + d0 + c4;
            *(float4*)&dt_t[row][c4] = *(const float4*)(dt + g);
            *(float4*)&x_t[row][c4]  = *(const float4*)(xb + g);
        }
        int brow = t >> 2, bc4 = (t & 3) * 4;
        const float* bcbase = xdbl + (size_t)(b*SEQLEN + l0 + brow)*96 + DT_RANK + bc4;
        *(float4*)&B_t[brow][bc4] = *(const float4*)bcbase;
        *(float4*)&C_t[brow][bc4] = *(const float4*)(bcbase + D_STATE);
    }
    float4 Al = *(const float4*)(A_log + d * D_STATE + s0);
    float As0 = -__expf(Al.x), As1 = -__expf(Al.y);
    float As2 = -__expf(Al.z), As3 = -__expf(Al.w);
    float Dd = Dvec[d];
    size_t idx = (((size_t)(b * NCHUNK + c)) * D_INNER + d) * D_STATE + s0;
    float4 hv = *(const float4*)&hinbuf[idx];
    float h0 = hv.x, h1 = hv.y, h2 = hv.z, h3 = hv.w;
    __syncthreads();

    #pragma unroll 4
    for (int l = 0; l < LC; l++) {
        float dtv = dt_t[l][ch];
        float xv  = x_t[l][ch];
        float dx  = dtv * xv;
        float4 Bv = *(float4*)&B_t[l][s0];
        float4 Cv = *(float4*)&C_t[l][s0];
        float a0 = __expf(dtv*As0), a1 = __expf(dtv*As1);
        float a2 = __expf(dtv*As2), a3 = __expf(dtv*As3);
        h0 = a0*h0 + dx*Bv.x;
        h1 = a1*h1 + dx*Bv.y;
        h2 = a2*h2 + dx*Bv.z;
        h3 = a3*h3 + dx*Bv.w;
        float p = h0*Cv.x + h1*Cv.y + h2*Cv.z + h3*Cv.w;
        p += __shfl_xor(p, 1);
        p += __shfl_xor(p, 2);
        if ((t & 3) == 0) y_t[l][ch] = p + xv * Dd;
    }
    __syncthreads();
    {
        int c4 = (t & 15) * 4;
        #pragma unroll
        for (int r = 0; r < 4; r++) {
            int row = (t >> 4) + r * 16;
            size_t g = (size_t)(b * SEQLEN + l0 + row) * D_INNER + d0 + c4;
            float4 y4 = *(float4*)&y_t[row][c4];
            float4 z4 = *(const float4*)(zio + g);
            y4.x *= z4.x; y4.y *= z4.y; y4.z *= z4.z; y4.w *= z4.w;
            *(float4*)(zio + g) = y4;
        }
    }
}

// ---------------------------------------------------------------------------
extern "C" void kernel_launch(void* const* d_in, const int* in_sizes, int n_in,
                              void* d_out, int out_size, void* d_ws, size_t ws_size,
                              hipStream_t stream)
{
    const float* x          = (const float*)d_in[0];
    const float* in_proj_w  = (const float*)d_in[1];
    const float* in_proj_b  = (const float*)d_in[2];
    const float* conv_w     = (const float*)d_in[3];
    const float* conv_b     = (const float*)d_in[4];
    const float* x_proj_w   = (const float*)d_in[5];
    const float* dt_proj_w  = (const float*)d_in[6];
    const float* dt_proj_b  = (const float*)d_in[7];
    const float* A_log      = (const float*)d_in[8];
    const float* Dv         = (const float*)d_in[9];
    const float* out_proj_w = (const float*)d_in[10];
    const float* out_proj_b = (const float*)d_in[11];
    float* out = (float*)d_out;

    float* ws   = (float*)d_ws;
    float* xpre = ws;
    float* xb   = ws + (size_t)M_TOTAL * D_INNER;
    float* zb   = ws + (size_t)2 * M_TOTAL * D_INNER;
    float* xdbl = ws + (size_t)3 * M_TOTAL * D_INNER;
    float* dt   = xpre;        // reuse: xpre dead after conv
    float* xpart = xpre;       // x_proj split-K partials, dead after reduce

    // Scan scratch lives in d_out (dead until final GEMM overwrites it).
    float* Pbuf = out;
    float* hbuf = out + (size_t)BATCH * NCHUNK * D_INNER * D_STATE;

    // 1) in_proj (f16 MFMA): xz = x @ in_proj_w^T + b ; split xpre / silu(z)
    {
        dim3 grid((2*D_INNER)/128, M_TOTAL/128);
        gemm_mfma<0><<<grid, 256, 0, stream>>>(
            x, D_MODEL, in_proj_w, D_MODEL, in_proj_b,
            xpre, zb, 2*D_INNER, D_MODEL);
    }
    // 2) causal depthwise conv + silu
    conv_silu_kernel<<<(BATCH*SEQLEN*D_INNER)/256, 256, 0, stream>>>(
        xpre, conv_w, conv_b, xb);
    // 3) x_proj (split-K f16 MFMA): xdbl = xb @ x_proj_w^T   (N = 96)
    {
        dim3 grid(M_TOTAL/64, XKSPLIT);
        xproj_mfma<<<grid, 256, 0, stream>>>(xb, x_proj_w, xpart);
        xproj_reduce<<<(M_TOTAL*96)/256, 256, 0, stream>>>(xpart, xdbl);
    }
    // 4) dt_proj (f32): dt = softplus(xdbl[:, :64] @ dt_proj_w^T + b)
    {
        dim3 grid(D_INNER/64, M_TOTAL/64);
        gemm_nt<64,64,16,4,4,2><<<grid, 256, 0, stream>>>(
            xdbl, 96, dt_proj_w, DT_RANK, dt_proj_b,
            dt, M_TOTAL, D_INNER, DT_RANK);
    }
    // 5) chunked selective scan (+D skip, +z gate) — overwrites zb
    {
        int nblk = BATCH * NCHUNK * (D_INNER / CHB);   // 1024
        scan_phase1<<<nblk, 256, 0, stream>>>(dt, xdbl, xb, A_log, Pbuf, hbuf);
        scan_carry<<<(BATCH*D_INNER*4)/256, 256, 0, stream>>>(Pbuf, hbuf);
        scan_phase2<<<nblk, 256, 0, stream>>>(dt, xdbl, xb, A_log, Dv, Pbuf, zb);
    }
    // 6) out_proj (f16 MFMA): out = ygated @ out_proj_w^T + b
    {
        dim3 grid(D_MODEL/128, M_TOTAL/128);
        gemm_mfma<3><<<grid, 256, 0, stream>>>(
            zb, D_INNER, out_proj_w, D_INNER, out_proj_b,
            out, nullptr, D_MODEL, D_INNER);
    }
}

// Round 8
// 280.746 us; speedup vs baseline: 5.0960x; 1.1159x over previous
//
#include <hip/hip_runtime.h>
#include <math.h>

#define D_STATE 16
#define D_CONV 4
#define DT_RANK 64
#define D_INNER 2048
#define D_MODEL 1024
#define BATCH 2
#define SEQLEN 1024
#define M_TOTAL (BATCH*SEQLEN)  // 2048
#define REG ((size_t)M_TOTAL*D_INNER)  // 4,194,304 elems

#define LC 64                    // scan chunk length
#define NCHUNK (SEQLEN/LC)       // 16
#define CHB 64                   // channels per scan block (4 s-lanes each)

#define XKSPLIT 16
#define XKCHUNK (D_INNER/XKSPLIT)   // 128
#define OSPLIT 4                 // out_proj split-K

typedef __fp16   h2s_t  __attribute__((ext_vector_type(2)));
typedef __fp16   h4s_t  __attribute__((ext_vector_type(4)));
typedef __fp16   h8s_t  __attribute__((ext_vector_type(8)));
typedef _Float16 half8  __attribute__((ext_vector_type(8)));  // MFMA operand
typedef float    floatx4 __attribute__((ext_vector_type(4)));

union HalfPack { h2s_t h2[4]; h8s_t h8; };

__device__ __forceinline__ float silu_f(float x) {
    return x / (1.0f + __expf(-x));
}
__device__ __forceinline__ float softplus_f(float x) {
    return fmaxf(x, 0.0f) + log1pf(__expf(-fabsf(x)));
}
__device__ __forceinline__ h8s_t pack8(const float4& v0, const float4& v1) {
    HalfPack p;
    p.h2[0] = __builtin_amdgcn_cvt_pkrtz(v0.x, v0.y);
    p.h2[1] = __builtin_amdgcn_cvt_pkrtz(v0.z, v0.w);
    p.h2[2] = __builtin_amdgcn_cvt_pkrtz(v1.x, v1.y);
    p.h2[3] = __builtin_amdgcn_cvt_pkrtz(v1.z, v1.w);
    return p.h8;
}
// async global->LDS, 16B per lane; LDS dst must be base + lane*16
__device__ __forceinline__ void gll16(const __fp16* g, __fp16* l) {
    __builtin_amdgcn_global_load_lds(
        (__attribute__((address_space(1))) const void*)g,
        (__attribute__((address_space(3))) void*)l, 16, 0, 0);
}

// ---------------------------------------------------------------------------
// f32 -> f16 convert (8 elems/thread)
// ---------------------------------------------------------------------------
__global__ __launch_bounds__(256)
void cvt_f16(const float* __restrict__ in, __fp16* __restrict__ out)
{
    size_t i = (size_t)blockIdx.x * 256 + threadIdx.x;
    const float* p = in + i * 8;
    *(h8s_t*)(out + i * 8) = pack8(*(const float4*)p, *(const float4*)(p + 4));
}

// out[m*D_MODEL+n] = bias[n]  (float4 per thread)
__global__ __launch_bounds__(256)
void out_init(float* __restrict__ out, const float* __restrict__ bias)
{
    size_t i = (size_t)blockIdx.x * 256 + threadIdx.x;
    int col = (int)((i * 4) & (D_MODEL - 1));
    *(float4*)(out + i * 4) = *(const float4*)(bias + col);
}

// ---------------------------------------------------------------------------
// f16-input MFMA NT GEMM with global_load_lds staging.
// Tile 128x128x32(halfs), 256 thr (4 waves), wave = 64x64 via 4x4 MFMA tiles.
// MODE 0 (in_proj): v=acc+bias[n]; n<D_INNER -> out0 f32; else out1=f16 silu(v)
// MODE 1 (out_proj split-K): atomicAdd(out0[m*N+n], acc)  (bias pre-applied)
// ---------------------------------------------------------------------------
template<int MODE, int SPLITK>
__global__ __launch_bounds__(256)
void gemm_gll(const __fp16* __restrict__ A, int lda,
              const __fp16* __restrict__ B, int ldb,
              const float* __restrict__ bias,
              float* __restrict__ out0, __fp16* __restrict__ out1,
              int N, int K)
{
    constexpr int BM = 128, BN = 128, BK = 32;   // BK in halfs (64 B rows)
    __shared__ __align__(16) __fp16 As[BM * BK];
    __shared__ __align__(16) __fp16 Bs[BN * BK];

    const int tid  = threadIdx.x;
    const int bm   = blockIdx.y * BM;
    const int bn   = blockIdx.x * BN;
    const int wave = tid >> 6;
    const int lane = tid & 63;
    const int wm   = (wave >> 1) * 64;
    const int wn   = (wave & 1) * 64;
    const int fr   = lane & 15;
    const int fkh  = (lane >> 4) * 8;   // frag k offset in halfs

    const int sr = tid >> 2;            // staging row 0..63
    const int sc = (tid & 3) * 8;       // staging col (halfs)

    const int kspan = K / SPLITK;
    const int k0    = (SPLITK > 1) ? blockIdx.z * kspan : 0;

    const __fp16* gA0 = A + (size_t)(bm + sr) * lda + k0 + sc;
    const __fp16* gA1 = A + (size_t)(bm + sr + 64) * lda + k0 + sc;
    const __fp16* gB0 = B + (size_t)(bn + sr) * ldb + k0 + sc;
    const __fp16* gB1 = B + (size_t)(bn + sr + 64) * ldb + k0 + sc;
    __fp16* lA0 = &As[sr * BK + sc];
    __fp16* lA1 = &As[(sr + 64) * BK + sc];
    __fp16* lB0 = &Bs[sr * BK + sc];
    __fp16* lB1 = &Bs[(sr + 64) * BK + sc];

    floatx4 zero = {0.f, 0.f, 0.f, 0.f};
    floatx4 acc[4][4];
    #pragma unroll
    for (int i = 0; i < 4; i++)
        #pragma unroll
        for (int j = 0; j < 4; j++) acc[i][j] = zero;

    for (int kt = 0; kt < kspan; kt += BK) {
        gll16(gA0 + kt, lA0);
        gll16(gA1 + kt, lA1);
        gll16(gB0 + kt, lB0);
        gll16(gB1 + kt, lB1);
        __syncthreads();

        half8 af[4], bf[4];
        #pragma unroll
        for (int i = 0; i < 4; i++)
            af[i] = *(half8*)&As[(wm + i*16 + fr) * BK + fkh];
        #pragma unroll
        for (int j = 0; j < 4; j++)
            bf[j] = *(half8*)&Bs[(wn + j*16 + fr) * BK + fkh];
        #pragma unroll
        for (int i = 0; i < 4; i++)
            #pragma unroll
            for (int j = 0; j < 4; j++)
                acc[i][j] = __builtin_amdgcn_mfma_f32_16x16x32_f16(
                    af[i], bf[j], acc[i][j], 0, 0, 0);
        __syncthreads();
    }

    // epilogue: C/D layout col=lane&15, row=(lane>>4)*4+reg
    const int rbase = (lane >> 4) * 4;
    #pragma unroll
    for (int i = 0; i < 4; i++) {
        #pragma unroll
        for (int j = 0; j < 4; j++) {
            int n = bn + wn + j*16 + fr;
            float bv = (MODE == 0) ? bias[n] : 0.0f;
            #pragma unroll
            for (int r = 0; r < 4; r++) {
                int m = bm + wm + i*16 + rbase + r;
                float v = acc[i][j][r] + bv;
                if (MODE == 0) {
                    if (n < D_INNER) out0[(size_t)m * D_INNER + n] = v;
                    else out1[(size_t)m * D_INNER + (n - D_INNER)] = (__fp16)silu_f(v);
                } else {
                    atomicAdd(out0 + (size_t)m * N + n, v);
                }
            }
        }
    }
}

// ---------------------------------------------------------------------------
// x_proj split-K f16 MFMA (pkrtz-staged from f32 xb; see round-5 comments).
// ---------------------------------------------------------------------------
__global__ __launch_bounds__(256)
void xproj_mfma(const float* __restrict__ A,
                const float* __restrict__ B,
                float* __restrict__ partials)
{
    constexpr int LDH = 40;
    __shared__ __fp16 As[64 * LDH];
    __shared__ __fp16 Bs[96 * LDH];

    const int tid = threadIdx.x;
    const int mt  = blockIdx.x * 64;
    const int p   = blockIdx.y;
    const int k0  = p * XKCHUNK;
    const int wave = tid >> 6;
    const int lane = tid & 63;
    const int fr = lane & 15;
    const int fk = (lane >> 4) * 8;

    floatx4 zero = {0.f, 0.f, 0.f, 0.f};
    floatx4 acc[6];
    #pragma unroll
    for (int j = 0; j < 6; j++) acc[j] = zero;

    for (int kt = 0; kt < XKCHUNK; kt += 32) {
        {
            int row = tid >> 2, kc = (tid & 3) * 8;
            const float* ga = A + (size_t)(mt + row) * D_INNER + k0 + kt + kc;
            *(h8s_t*)&As[row * LDH + kc] =
                pack8(*(const float4*)ga, *(const float4*)(ga + 4));
        }
        {
            int row = tid >> 2, kc = (tid & 3) * 8;
            const float* gb = B + (size_t)row * D_INNER + k0 + kt + kc;
            *(h8s_t*)&Bs[row * LDH + kc] =
                pack8(*(const float4*)gb, *(const float4*)(gb + 4));
            if (tid < 128) {
                int c2 = tid + 256;
                int row2 = c2 >> 2, kc2 = (c2 & 3) * 8;
                const float* gb2 = B + (size_t)row2 * D_INNER + k0 + kt + kc2;
                *(h8s_t*)&Bs[row2 * LDH + kc2] =
                    pack8(*(const float4*)gb2, *(const float4*)(gb2 + 4));
            }
        }
        __syncthreads();

        half8 af = *(half8*)&As[(wave * 16 + fr) * LDH + fk];
        #pragma unroll
        for (int j = 0; j < 6; j++) {
            half8 bf = *(half8*)&Bs[(j * 16 + fr) * LDH + fk];
            acc[j] = __builtin_amdgcn_mfma_f32_16x16x32_f16(af, bf, acc[j], 0, 0, 0);
        }
        __syncthreads();
    }

    const int rbase = (lane >> 4) * 4;
    float* outp = partials + ((size_t)p * M_TOTAL + mt + wave * 16) * 96;
    #pragma unroll
    for (int j = 0; j < 6; j++) {
        int n = j * 16 + fr;
        #pragma unroll
        for (int r = 0; r < 4; r++)
            outp[(size_t)(rbase + r) * 96 + n] = acc[j][r];
    }
}

__global__ __launch_bounds__(256)
void xproj_reduce(const float* __restrict__ partials, float* __restrict__ xdbl)
{
    int i = blockIdx.x * 256 + threadIdx.x;
    float s = 0.0f;
    #pragma unroll
    for (int p = 0; p < XKSPLIT; p++)
        s += partials[(size_t)p * M_TOTAL * 96 + i];
    xdbl[i] = s;
}

// ---------------------------------------------------------------------------
// f32 vector-ALU NT GEMM (dt_proj). MODE 2: softplus(acc + bias[n])
// ---------------------------------------------------------------------------
template<int BM, int BN, int BK, int TM, int TN, int MODE>
__global__ __launch_bounds__((BM/TM)*(BN/TN))
void gemm_nt(const float* __restrict__ A, int lda,
             const float* __restrict__ B, int ldb,
             const float* __restrict__ bias,
             float* __restrict__ out0,
             int M, int N, int K)
{
    constexpr int THREADS = (BM/TM)*(BN/TN);
    __shared__ float As[BK][BM+4];
    __shared__ float Bs[BK][BN+4];
    const int tid = threadIdx.x;
    const int bm = blockIdx.y * BM;
    const int bn = blockIdx.x * BN;
    const int tx = tid % (BN/TN);
    const int ty = tid / (BN/TN);

    float acc[TM][TN];
    #pragma unroll
    for (int i = 0; i < TM; i++)
        #pragma unroll
        for (int j = 0; j < TN; j++) acc[i][j] = 0.0f;

    constexpr int F4_PER_ROW = BK / 4;
    constexpr int A_ROWS_PER_ITER = THREADS / F4_PER_ROW;
    constexpr int B_ROWS_PER_ITER = THREADS / F4_PER_ROW;

    for (int kt = 0; kt < K; kt += BK) {
        #pragma unroll
        for (int r = 0; r < BM; r += A_ROWS_PER_ITER) {
            int row = r + tid / F4_PER_ROW;
            int kc  = (tid % F4_PER_ROW) * 4;
            float4 v = *(const float4*)(A + (size_t)(bm + row) * lda + kt + kc);
            As[kc+0][row] = v.x; As[kc+1][row] = v.y;
            As[kc+2][row] = v.z; As[kc+3][row] = v.w;
        }
        #pragma unroll
        for (int r = 0; r < BN; r += B_ROWS_PER_ITER) {
            int row = r + tid / F4_PER_ROW;
            int kc  = (tid % F4_PER_ROW) * 4;
            float4 v = *(const float4*)(B + (size_t)(bn + row) * ldb + kt + kc);
            Bs[kc+0][row] = v.x; Bs[kc+1][row] = v.y;
            Bs[kc+2][row] = v.z; Bs[kc+3][row] = v.w;
        }
        __syncthreads();
        #pragma unroll
        for (int k = 0; k < BK; k++) {
            float ra[TM], rb[TN];
            #pragma unroll
            for (int i = 0; i < TM; i++) ra[i] = As[k][ty*TM + i];
            #pragma unroll
            for (int j = 0; j < TN; j++) rb[j] = Bs[k][tx*TN + j];
            #pragma unroll
            for (int i = 0; i < TM; i++)
                #pragma unroll
                for (int j = 0; j < TN; j++) acc[i][j] += ra[i] * rb[j];
        }
        __syncthreads();
    }

    #pragma unroll
    for (int i = 0; i < TM; i++) {
        int m = bm + ty*TM + i;
        #pragma unroll
        for (int j = 0; j < TN; j++) {
            int n = bn + tx*TN + j;
            float v = acc[i][j];
            if (MODE == 1) out0[(size_t)m * N + n] = v;
            else           out0[(size_t)m * N + n] = softplus_f(v + bias[n]);
        }
    }
}

// ---------------------------------------------------------------------------
// Causal depthwise conv (4 taps, left pad 3) + SiLU.  Layout (b, l, c).
// ---------------------------------------------------------------------------
__global__ __launch_bounds__(256)
void conv_silu_kernel(const float* __restrict__ xpre,
                      const float* __restrict__ conv_w,
                      const float* __restrict__ conv_b,
                      float* __restrict__ xb)
{
    int idx = blockIdx.x * blockDim.x + threadIdx.x;
    int c = idx % D_INNER;
    int l = (idx / D_INNER) % SEQLEN;
    int b = idx / (D_INNER * SEQLEN);
    const float* base = xpre + (size_t)b * SEQLEN * D_INNER + c;
    float w0 = conv_w[c*4+0], w1 = conv_w[c*4+1];
    float w2 = conv_w[c*4+2], w3 = conv_w[c*4+3];
    float acc = conv_b[c];
    if (l >= 3) acc += w0 * base[(l-3) * D_INNER];
    if (l >= 2) acc += w1 * base[(l-2) * D_INNER];
    if (l >= 1) acc += w2 * base[(l-1) * D_INNER];
    acc += w3 * base[l * D_INNER];
    xb[idx] = silu_f(acc);
}

// ---------------------------------------------------------------------------
// Chunked selective scan, state-quad threads (4 states/thread, 4 lanes/chan).
// ---------------------------------------------------------------------------
__global__ __launch_bounds__(256)
void scan_phase1(const float* __restrict__ dt,
                 const float* __restrict__ xdbl,
                 const float* __restrict__ xb,
                 const float* __restrict__ A_log,
                 float* __restrict__ Pbuf, float* __restrict__ hbuf)
{
    int bx = blockIdx.x;
    int dg = bx & 31;
    int c  = (bx >> 5) & (NCHUNK - 1);
    int b  = bx >> 9;
    int d0 = dg * CHB;
    int t  = threadIdx.x;
    int s0 = (t & 3) * 4;
    int ch = t >> 2;
    int d  = d0 + ch;
    int l0 = c * LC;

    __shared__ __align__(16) float dt_t[LC][CHB];
    __shared__ __align__(16) float x_t[LC][CHB];
    __shared__ __align__(16) float B_t[LC][D_STATE];
    {
        int c4 = (t & 15) * 4;
        #pragma unroll
        for (int r = 0; r < 4; r++) {
            int row = (t >> 4) + r * 16;
            size_t g = (size_t)(b * SEQLEN + l0 + row) * D_INNER + d0 + c4;
            *(float4*)&dt_t[row][c4] = *(const float4*)(dt + g);
            *(float4*)&x_t[row][c4]  = *(const float4*)(xb + g);
        }
        int brow = t >> 2, bc4 = (t & 3) * 4;
        *(float4*)&B_t[brow][bc4] =
            *(const float4*)(xdbl + (size_t)(b*SEQLEN + l0 + brow)*96 + DT_RANK + bc4);
    }
    float4 Al = *(const float4*)(A_log + d * D_STATE + s0);
    float As0 = -__expf(Al.x), As1 = -__expf(Al.y);
    float As2 = -__expf(Al.z), As3 = -__expf(Al.w);
    __syncthreads();

    float h0=0,h1=0,h2=0,h3=0, P0=1,P1=1,P2=1,P3=1;
    #pragma unroll 4
    for (int l = 0; l < LC; l++) {
        float dtv = dt_t[l][ch];
        float dx  = dtv * x_t[l][ch];
        float4 Bv = *(float4*)&B_t[l][s0];
        float a0 = __expf(dtv*As0), a1 = __expf(dtv*As1);
        float a2 = __expf(dtv*As2), a3 = __expf(dtv*As3);
        h0 = a0*h0 + dx*Bv.x;  P0 *= a0;
        h1 = a1*h1 + dx*Bv.y;  P1 *= a1;
        h2 = a2*h2 + dx*Bv.z;  P2 *= a2;
        h3 = a3*h3 + dx*Bv.w;  P3 *= a3;
    }
    size_t idx = (((size_t)(b * NCHUNK + c)) * D_INNER + d) * D_STATE + s0;
    float4 Pv = {P0,P1,P2,P3}, hv = {h0,h1,h2,h3};
    *(float4*)&Pbuf[idx] = Pv;
    *(float4*)&hbuf[idx] = hv;
}

__global__ __launch_bounds__(256)
void scan_carry(float* __restrict__ Pbuf, const float* __restrict__ hbuf)
{
    int t = blockIdx.x * 256 + threadIdx.x;
    int s0 = (t & 3) * 4;
    int bd = t >> 2;
    int d = bd & (D_INNER - 1);
    int b = bd >> 11;
    float4 h = {0,0,0,0};
    #pragma unroll
    for (int c = 0; c < NCHUNK; c++) {
        size_t idx = (((size_t)(b * NCHUNK + c)) * D_INNER + d) * D_STATE + s0;
        float4 Pc = *(float4*)&Pbuf[idx];
        float4 hl = *(const float4*)&hbuf[idx];
        *(float4*)&Pbuf[idx] = h;
        h.x = Pc.x*h.x + hl.x;  h.y = Pc.y*h.y + hl.y;
        h.z = Pc.z*h.z + hl.z;  h.w = Pc.w*h.w + hl.w;
    }
}

__global__ __launch_bounds__(256)
void scan_phase2(const float* __restrict__ dt,
                 const float* __restrict__ xdbl,
                 const float* __restrict__ xb,
                 const float* __restrict__ A_log,
                 const float* __restrict__ Dvec,
                 const float* __restrict__ hinbuf,
                 const __fp16* __restrict__ zh,   // silu(z) f16
                 __fp16* __restrict__ yh)         // gated y f16 (out_proj A)
{
    int bx = blockIdx.x;
    int dg = bx & 31;
    int c  = (bx >> 5) & (NCHUNK - 1);
    int b  = bx >> 9;
    int d0 = dg * CHB;
    int t  = threadIdx.x;
    int s0 = (t & 3) * 4;
    int ch = t >> 2;
    int d  = d0 + ch;
    int l0 = c * LC;

    __shared__ __align__(16) float dt_t[LC][CHB];
    __shared__ __align__(16) float x_t[LC][CHB];
    __shared__ __align__(16) float B_t[LC][D_STATE];
    __shared__ __align__(16) float C_t[LC][D_STATE];
    __shared__ __align__(16) float y_t[LC][CHB];
    {
        int c4 = (t & 15) * 4;
        #pragma unroll
        for (int r = 0; r < 4; r++) {
            int row = (t >> 4) + r * 16;
            size_t g = (size_t)(b * SEQLEN + l0 + row) * D_INNER + d0 + c4;
            *(float4*)&dt_t[row][c4] = *(const float4*)(dt + g);
            *(float4*)&x_t[row][c4]  = *(const float4*)(xb + g);
        }
        int brow = t >> 2, bc4 = (t & 3) * 4;
        const float* bcbase = xdbl + (size_t)(b*SEQLEN + l0 + brow)*96 + DT_RANK + bc4;
        *(float4*)&B_t[brow][bc4] = *(const float4*)bcbase;
        *(float4*)&C_t[brow][bc4] = *(const float4*)(bcbase + D_STATE);
    }
    float4 Al = *(const float4*)(A_log + d * D_STATE + s0);
    float As0 = -__expf(Al.x), As1 = -__expf(Al.y);
    float As2 = -__expf(Al.z), As3 = -__expf(Al.w);
    float Dd = Dvec[d];
    size_t idx = (((size_t)(b * NCHUNK + c)) * D_INNER + d) * D_STATE + s0;
    float4 hv = *(const float4*)&hinbuf[idx];
    float h0 = hv.x, h1 = hv.y, h2 = hv.z, h3 = hv.w;
    __syncthreads();

    #pragma unroll 4
    for (int l = 0; l < LC; l++) {
        float dtv = dt_t[l][ch];
        float xv  = x_t[l][ch];
        float dx  = dtv * xv;
        float4 Bv = *(float4*)&B_t[l][s0];
        float4 Cv = *(float4*)&C_t[l][s0];
        float a0 = __expf(dtv*As0), a1 = __expf(dtv*As1);
        float a2 = __expf(dtv*As2), a3 = __expf(dtv*As3);
        h0 = a0*h0 + dx*Bv.x;
        h1 = a1*h1 + dx*Bv.y;
        h2 = a2*h2 + dx*Bv.z;
        h3 = a3*h3 + dx*Bv.w;
        float p = h0*Cv.x + h1*Cv.y + h2*Cv.z + h3*Cv.w;
        p += __shfl_xor(p, 1);
        p += __shfl_xor(p, 2);
        if ((t & 3) == 0) y_t[l][ch] = p + xv * Dd;
    }
    __syncthreads();
    {
        int c4 = (t & 15) * 4;
        #pragma unroll
        for (int r = 0; r < 4; r++) {
            int row = (t >> 4) + r * 16;
            size_t g = (size_t)(b * SEQLEN + l0 + row) * D_INNER + d0 + c4;
            float4 y4 = *(float4*)&y_t[row][c4];
            h4s_t z4 = *(const h4s_t*)(zh + g);
            h4s_t o;
            o[0] = (__fp16)(y4.x * (float)z4[0]);
            o[1] = (__fp16)(y4.y * (float)z4[1]);
            o[2] = (__fp16)(y4.z * (float)z4[2]);
            o[3] = (__fp16)(y4.w * (float)z4[3]);
            *(h4s_t*)(yh + g) = o;
        }
    }
}

// ---------------------------------------------------------------------------
extern "C" void kernel_launch(void* const* d_in, const int* in_sizes, int n_in,
                              void* d_out, int out_size, void* d_ws, size_t ws_size,
                              hipStream_t stream)
{
    const float* x          = (const float*)d_in[0];
    const float* in_proj_w  = (const float*)d_in[1];
    const float* in_proj_b  = (const float*)d_in[2];
    const float* conv_w     = (const float*)d_in[3];
    const float* conv_b     = (const float*)d_in[4];
    const float* x_proj_w   = (const float*)d_in[5];
    const float* dt_proj_w  = (const float*)d_in[6];
    const float* dt_proj_b  = (const float*)d_in[7];
    const float* A_log      = (const float*)d_in[8];
    const float* Dv         = (const float*)d_in[9];
    const float* out_proj_w = (const float*)d_in[10];
    const float* out_proj_b = (const float*)d_in[11];
    float* out = (float*)d_out;

    // ws layout (51.1 MB total):
    //  A region [0, REG): xpre -> xpart -> dt -> wh2(f16)
    //  B region [REG, 2*REG): wh1(f16)+xh(f16) -> xb(f32)
    //  xdbl [2*REG, 2*REG+196608)
    //  zh (f16, REG halfs), yh (f16, REG halfs)
    float* ws   = (float*)d_ws;
    float* xpre = ws;                       // A region
    float* xb   = ws + REG;                 // B region
    float* xdbl = ws + 2 * REG;
    __fp16* zh  = (__fp16*)(ws + 2 * REG + (size_t)M_TOTAL * 96);
    __fp16* yh  = zh + REG;
    float* dt    = xpre;
    float* xpart = xpre;
    __fp16* wh2  = (__fp16*)xpre;           // after scan, dt dead
    __fp16* wh1  = (__fp16*)xb;             // before conv writes xb
    __fp16* xh   = (__fp16*)(xb + REG / 2); // before conv writes xb

    // Scan scratch lives in d_out (dead until out_init overwrites it).
    float* Pbuf = out;
    float* hbuf = out + (size_t)BATCH * NCHUNK * D_INNER * D_STATE;

    // 0) f32->f16 conversions for in_proj operands
    cvt_f16<<<(M_TOTAL*D_MODEL/8)/256, 256, 0, stream>>>(x, xh);
    cvt_f16<<<(2*D_INNER*D_MODEL/8)/256, 256, 0, stream>>>(in_proj_w, wh1);

    // 1) in_proj (f16 MFMA + global_load_lds): xpre f32 / zh f16 silu
    {
        dim3 grid((2*D_INNER)/128, M_TOTAL/128, 1);
        gemm_gll<0,1><<<grid, 256, 0, stream>>>(
            xh, D_MODEL, wh1, D_MODEL, in_proj_b,
            xpre, zh, 2*D_INNER, D_MODEL);
    }
    // 2) causal depthwise conv + silu (overwrites wh1/xh region)
    conv_silu_kernel<<<(BATCH*SEQLEN*D_INNER)/256, 256, 0, stream>>>(
        xpre, conv_w, conv_b, xb);
    // 3) x_proj (split-K f16 MFMA): xdbl = xb @ x_proj_w^T   (N = 96)
    {
        dim3 grid(M_TOTAL/64, XKSPLIT);
        xproj_mfma<<<grid, 256, 0, stream>>>(xb, x_proj_w, xpart);
        xproj_reduce<<<(M_TOTAL*96)/256, 256, 0, stream>>>(xpart, xdbl);
    }
    // 4) dt_proj (f32): dt = softplus(xdbl[:, :64] @ dt_proj_w^T + b)
    {
        dim3 grid(D_INNER/64, M_TOTAL/64);
        gemm_nt<64,64,16,4,4,2><<<grid, 256, 0, stream>>>(
            xdbl, 96, dt_proj_w, DT_RANK, dt_proj_b,
            dt, M_TOTAL, D_INNER, DT_RANK);
    }
    // 5) chunked selective scan (+D skip, +z gate) — writes yh f16
    {
        int nblk = BATCH * NCHUNK * (D_INNER / CHB);   // 1024
        scan_phase1<<<nblk, 256, 0, stream>>>(dt, xdbl, xb, A_log, Pbuf, hbuf);
        scan_carry<<<(BATCH*D_INNER*4)/256, 256, 0, stream>>>(Pbuf, hbuf);
        scan_phase2<<<nblk, 256, 0, stream>>>(dt, xdbl, xb, A_log, Dv, Pbuf, zh, yh);
    }
    // 6) out_proj: convert weights, init out=bias, split-K atomic GEMM
    cvt_f16<<<(D_MODEL*D_INNER/8)/256, 256, 0, stream>>>(out_proj_w, wh2);
    out_init<<<(M_TOTAL*D_MODEL/4)/256, 256, 0, stream>>>(out, out_proj_b);
    {
        dim3 grid(D_MODEL/128, M_TOTAL/128, OSPLIT);
        gemm_gll<1,OSPLIT><<<grid, 256, 0, stream>>>(
            yh, D_INNER, wh2, D_INNER, nullptr,
            out, nullptr, D_MODEL, D_INNER);
    }
}

// Round 9
// 264.118 us; speedup vs baseline: 5.4168x; 1.0630x over previous
//
#include <hip/hip_runtime.h>
#include <math.h>

#define D_STATE 16
#define D_CONV 4
#define DT_RANK 64
#define D_INNER 2048
#define D_MODEL 1024
#define BATCH 2
#define SEQLEN 1024
#define M_TOTAL (BATCH*SEQLEN)  // 2048
#define REG ((size_t)M_TOTAL*D_INNER)  // 4,194,304 elems

#define LC 64                    // scan chunk length
#define NCHUNK (SEQLEN/LC)       // 16
#define CHB 64                   // channels per scan block (4 s-lanes each)

#define XKSPLIT 16
#define XKCHUNK (D_INNER/XKSPLIT)   // 128
#define OSPLIT 4                 // out_proj split-K

typedef __fp16   h2s_t  __attribute__((ext_vector_type(2)));
typedef __fp16   h4s_t  __attribute__((ext_vector_type(4)));
typedef __fp16   h8s_t  __attribute__((ext_vector_type(8)));
typedef _Float16 half8  __attribute__((ext_vector_type(8)));  // MFMA operand
typedef float    floatx4 __attribute__((ext_vector_type(4)));

union HalfPack { h2s_t h2[4]; h8s_t h8; };

__device__ __forceinline__ float silu_f(float x) {
    return x / (1.0f + __expf(-x));
}
__device__ __forceinline__ float softplus_f(float x) {
    return fmaxf(x, 0.0f) + log1pf(__expf(-fabsf(x)));
}
__device__ __forceinline__ h8s_t pack8(const float4& v0, const float4& v1) {
    HalfPack p;
    p.h2[0] = __builtin_amdgcn_cvt_pkrtz(v0.x, v0.y);
    p.h2[1] = __builtin_amdgcn_cvt_pkrtz(v0.z, v0.w);
    p.h2[2] = __builtin_amdgcn_cvt_pkrtz(v1.x, v1.y);
    p.h2[3] = __builtin_amdgcn_cvt_pkrtz(v1.z, v1.w);
    return p.h8;
}
// async global->LDS, 16B per lane; LDS dst must be wave base + lane*16
__device__ __forceinline__ void gll16(const __fp16* g, __fp16* l) {
    __builtin_amdgcn_global_load_lds(
        (__attribute__((address_space(1))) const void*)g,
        (__attribute__((address_space(3))) void*)l, 16, 0, 0);
}

// ---------------------------------------------------------------------------
// One-shot f32->f16 conversion of x + all GEMM weights (segmented flat index).
// ---------------------------------------------------------------------------
#define N0 ((size_t)M_TOTAL*D_MODEL/8)       // x
#define N1 ((size_t)2*D_INNER*D_MODEL/8)     // in_proj_w
#define N2 ((size_t)D_MODEL*D_INNER/8)       // out_proj_w
#define N3 ((size_t)96*D_INNER/8)            // x_proj_w
#define N4 ((size_t)D_INNER*DT_RANK/8)       // dt_proj_w
#define NCVT (N0+N1+N2+N3+N4)                // 1,089,536 chunks

__global__ __launch_bounds__(256)
void cvt_all(const float* __restrict__ x,  const float* __restrict__ w1,
             const float* __restrict__ w2, const float* __restrict__ xpw,
             const float* __restrict__ dtw,
             __fp16* __restrict__ xh,  __fp16* __restrict__ wh1,
             __fp16* __restrict__ wh2, __fp16* __restrict__ xpwh,
             __fp16* __restrict__ dtwh)
{
    size_t i = (size_t)blockIdx.x * 256 + threadIdx.x;
    if (i >= NCVT) return;
    const float* src; __fp16* dst; size_t off;
    if      (i < N0)          { src = x;   dst = xh;   off = i; }
    else if (i < N0+N1)       { src = w1;  dst = wh1;  off = i - N0; }
    else if (i < N0+N1+N2)    { src = w2;  dst = wh2;  off = i - N0 - N1; }
    else if (i < N0+N1+N2+N3) { src = xpw; dst = xpwh; off = i - N0 - N1 - N2; }
    else                      { src = dtw; dst = dtwh; off = i - N0 - N1 - N2 - N3; }
    const float* p = src + off * 8;
    *(h8s_t*)(dst + off * 8) = pack8(*(const float4*)p, *(const float4*)(p + 4));
}

// out[m*D_MODEL+n] = bias[n]
__global__ __launch_bounds__(256)
void out_init(float* __restrict__ out, const float* __restrict__ bias)
{
    size_t i = (size_t)blockIdx.x * 256 + threadIdx.x;
    int col = (int)((i * 4) & (D_MODEL - 1));
    *(float4*)(out + i * 4) = *(const float4*)(bias + col);
}

// ---------------------------------------------------------------------------
// f16-input MFMA NT GEMM with global_load_lds staging (128x128x32).
// MODE 0 (in_proj): v=acc+bias[n]; n<D_INNER -> out0 f32; else out1=f16 silu(v)
// MODE 1 (out_proj split-K): atomicAdd(out0[m*N+n], acc)  (bias pre-applied)
// ---------------------------------------------------------------------------
template<int MODE, int SPLITK>
__global__ __launch_bounds__(256)
void gemm_gll(const __fp16* __restrict__ A, int lda,
              const __fp16* __restrict__ B, int ldb,
              const float* __restrict__ bias,
              float* __restrict__ out0, __fp16* __restrict__ out1,
              int N, int K)
{
    constexpr int BM = 128, BN = 128, BK = 32;   // BK in halfs (64 B rows)
    __shared__ __align__(16) __fp16 As[BM * BK];
    __shared__ __align__(16) __fp16 Bs[BN * BK];

    const int tid  = threadIdx.x;
    const int bm   = blockIdx.y * BM;
    const int bn   = blockIdx.x * BN;
    const int wave = tid >> 6;
    const int lane = tid & 63;
    const int wm   = (wave >> 1) * 64;
    const int wn   = (wave & 1) * 64;
    const int fr   = lane & 15;
    const int fkh  = (lane >> 4) * 8;

    const int sr = tid >> 2;
    const int sc = (tid & 3) * 8;

    const int kspan = K / SPLITK;
    const int k0    = (SPLITK > 1) ? blockIdx.z * kspan : 0;

    const __fp16* gA0 = A + (size_t)(bm + sr) * lda + k0 + sc;
    const __fp16* gA1 = A + (size_t)(bm + sr + 64) * lda + k0 + sc;
    const __fp16* gB0 = B + (size_t)(bn + sr) * ldb + k0 + sc;
    const __fp16* gB1 = B + (size_t)(bn + sr + 64) * ldb + k0 + sc;
    __fp16* lA0 = &As[sr * BK + sc];
    __fp16* lA1 = &As[(sr + 64) * BK + sc];
    __fp16* lB0 = &Bs[sr * BK + sc];
    __fp16* lB1 = &Bs[(sr + 64) * BK + sc];

    floatx4 zero = {0.f, 0.f, 0.f, 0.f};
    floatx4 acc[4][4];
    #pragma unroll
    for (int i = 0; i < 4; i++)
        #pragma unroll
        for (int j = 0; j < 4; j++) acc[i][j] = zero;

    for (int kt = 0; kt < kspan; kt += BK) {
        gll16(gA0 + kt, lA0);
        gll16(gA1 + kt, lA1);
        gll16(gB0 + kt, lB0);
        gll16(gB1 + kt, lB1);
        __syncthreads();

        half8 af[4], bf[4];
        #pragma unroll
        for (int i = 0; i < 4; i++)
            af[i] = *(half8*)&As[(wm + i*16 + fr) * BK + fkh];
        #pragma unroll
        for (int j = 0; j < 4; j++)
            bf[j] = *(half8*)&Bs[(wn + j*16 + fr) * BK + fkh];
        #pragma unroll
        for (int i = 0; i < 4; i++)
            #pragma unroll
            for (int j = 0; j < 4; j++)
                acc[i][j] = __builtin_amdgcn_mfma_f32_16x16x32_f16(
                    af[i], bf[j], acc[i][j], 0, 0, 0);
        __syncthreads();
    }

    const int rbase = (lane >> 4) * 4;
    #pragma unroll
    for (int i = 0; i < 4; i++) {
        #pragma unroll
        for (int j = 0; j < 4; j++) {
            int n = bn + wn + j*16 + fr;
            float bv = (MODE == 0) ? bias[n] : 0.0f;
            #pragma unroll
            for (int r = 0; r < 4; r++) {
                int m = bm + wm + i*16 + rbase + r;
                float v = acc[i][j][r] + bv;
                if (MODE == 0) {
                    if (n < D_INNER) out0[(size_t)m * D_INNER + n] = v;
                    else out1[(size_t)m * D_INNER + (n - D_INNER)] = (__fp16)silu_f(v);
                } else {
                    atomicAdd(out0 + (size_t)m * N + n, v);
                }
            }
        }
    }
}

// ---------------------------------------------------------------------------
// x_proj split-K, gll staging from f16: partials[p][m][96].
// ---------------------------------------------------------------------------
__global__ __launch_bounds__(256)
void xproj_gll(const __fp16* __restrict__ A,      // xbh, lda = D_INNER
               const __fp16* __restrict__ B,      // xpwh (96 x D_INNER)
               float* __restrict__ partials)
{
    __shared__ __align__(16) __fp16 As[64 * 32];
    __shared__ __align__(16) __fp16 Bs[96 * 32];

    const int tid = threadIdx.x;
    const int mt  = blockIdx.x * 64;
    const int p   = blockIdx.y;
    const int k0  = p * XKCHUNK;
    const int wave = tid >> 6;
    const int lane = tid & 63;
    const int fr = lane & 15;
    const int fkh = (lane >> 4) * 8;

    floatx4 zero = {0.f, 0.f, 0.f, 0.f};
    floatx4 acc[6];
    #pragma unroll
    for (int j = 0; j < 6; j++) acc[j] = zero;

    for (int kt = 0; kt < XKCHUNK; kt += 32) {
        {
            int row = tid >> 2, col = (tid & 3) * 8;
            gll16(A + (size_t)(mt + row) * D_INNER + k0 + kt + col, &As[tid * 8]);
            gll16(B + (size_t)row * D_INNER + k0 + kt + col, &Bs[tid * 8]);
            if (tid < 128) {
                int c = tid + 256;
                gll16(B + (size_t)(c >> 2) * D_INNER + k0 + kt + (c & 3) * 8,
                      &Bs[c * 8]);
            }
        }
        __syncthreads();

        half8 af = *(half8*)&As[(wave * 16 + fr) * 32 + fkh];
        #pragma unroll
        for (int j = 0; j < 6; j++) {
            half8 bf = *(half8*)&Bs[(j * 16 + fr) * 32 + fkh];
            acc[j] = __builtin_amdgcn_mfma_f32_16x16x32_f16(af, bf, acc[j], 0, 0, 0);
        }
        __syncthreads();
    }

    const int rbase = (lane >> 4) * 4;
    float* outp = partials + ((size_t)p * M_TOTAL + mt + wave * 16) * 96;
    #pragma unroll
    for (int j = 0; j < 6; j++) {
        int n = j * 16 + fr;
        #pragma unroll
        for (int r = 0; r < 4; r++)
            outp[(size_t)(rbase + r) * 96 + n] = acc[j][r];
    }
}

// reduce partials -> xdbl f32 (all 96) + dtr_h f16 (first 64 cols)
__global__ __launch_bounds__(256)
void xproj_reduce(const float* __restrict__ partials,
                  float* __restrict__ xdbl, __fp16* __restrict__ dtrh)
{
    int i = blockIdx.x * 256 + threadIdx.x;
    float s = 0.0f;
    #pragma unroll
    for (int p = 0; p < XKSPLIT; p++)
        s += partials[(size_t)p * M_TOTAL * 96 + i];
    xdbl[i] = s;
    int col = i % 96;
    if (col < DT_RANK) dtrh[(size_t)(i / 96) * DT_RANK + col] = (__fp16)s;
}

// ---------------------------------------------------------------------------
// dt_proj f16 MFMA: dt = softplus(dtr @ dtw^T + b), K=64, output f16.
// Tile 128x128, one LDS fill (K=64 = 2 MFMA k-steps), gll staging.
// ---------------------------------------------------------------------------
__global__ __launch_bounds__(256)
void dtproj_mfma(const __fp16* __restrict__ A,    // dtr_h (M x 64)
                 const __fp16* __restrict__ B,    // dtwh (D_INNER x 64)
                 const float* __restrict__ bias,
                 __fp16* __restrict__ dth)
{
    __shared__ __align__(16) __fp16 As[128 * 64];
    __shared__ __align__(16) __fp16 Bs[128 * 64];

    const int tid  = threadIdx.x;
    const int bm   = blockIdx.y * 128;
    const int bn   = blockIdx.x * 128;
    const int wave = tid >> 6;
    const int lane = tid & 63;
    const int wm   = (wave >> 1) * 64;
    const int wn   = (wave & 1) * 64;
    const int fr   = lane & 15;
    const int fkh  = (lane >> 4) * 8;

    #pragma unroll
    for (int r = 0; r < 4; r++) {
        int c = tid + 256 * r;
        int row = c >> 3, col = (c & 7) * 8;
        gll16(A + (size_t)(bm + row) * DT_RANK + col, &As[c * 8]);
        gll16(B + (size_t)(bn + row) * DT_RANK + col, &Bs[c * 8]);
    }
    __syncthreads();

    floatx4 zero = {0.f, 0.f, 0.f, 0.f};
    floatx4 acc[4][4];
    #pragma unroll
    for (int i = 0; i < 4; i++)
        #pragma unroll
        for (int j = 0; j < 4; j++) acc[i][j] = zero;

    #pragma unroll
    for (int ks = 0; ks < 64; ks += 32) {
        half8 af[4], bf[4];
        #pragma unroll
        for (int i = 0; i < 4; i++)
            af[i] = *(half8*)&As[(wm + i*16 + fr) * 64 + ks + fkh];
        #pragma unroll
        for (int j = 0; j < 4; j++)
            bf[j] = *(half8*)&Bs[(wn + j*16 + fr) * 64 + ks + fkh];
        #pragma unroll
        for (int i = 0; i < 4; i++)
            #pragma unroll
            for (int j = 0; j < 4; j++)
                acc[i][j] = __builtin_amdgcn_mfma_f32_16x16x32_f16(
                    af[i], bf[j], acc[i][j], 0, 0, 0);
    }

    const int rbase = (lane >> 4) * 4;
    #pragma unroll
    for (int i = 0; i < 4; i++) {
        #pragma unroll
        for (int j = 0; j < 4; j++) {
            int n = bn + wn + j*16 + fr;
            float bv = bias[n];
            #pragma unroll
            for (int r = 0; r < 4; r++) {
                int m = bm + wm + i*16 + rbase + r;
                dth[(size_t)m * D_INNER + n] = (__fp16)softplus_f(acc[i][j][r] + bv);
            }
        }
    }
}

// ---------------------------------------------------------------------------
// Causal depthwise conv (4 taps, left pad 3) + SiLU -> f16.  Layout (b,l,c).
// ---------------------------------------------------------------------------
__global__ __launch_bounds__(256)
void conv_silu_kernel(const float* __restrict__ xpre,
                      const float* __restrict__ conv_w,
                      const float* __restrict__ conv_b,
                      __fp16* __restrict__ xbh)
{
    int idx = blockIdx.x * blockDim.x + threadIdx.x;
    int c = idx % D_INNER;
    int l = (idx / D_INNER) % SEQLEN;
    int b = idx / (D_INNER * SEQLEN);
    const float* base = xpre + (size_t)b * SEQLEN * D_INNER + c;
    float w0 = conv_w[c*4+0], w1 = conv_w[c*4+1];
    float w2 = conv_w[c*4+2], w3 = conv_w[c*4+3];
    float acc = conv_b[c];
    if (l >= 3) acc += w0 * base[(l-3) * D_INNER];
    if (l >= 2) acc += w1 * base[(l-2) * D_INNER];
    if (l >= 1) acc += w2 * base[(l-1) * D_INNER];
    acc += w3 * base[l * D_INNER];
    xbh[idx] = (__fp16)silu_f(acc);
}

// ---------------------------------------------------------------------------
// Chunked selective scan, state-quad threads; f16 global dt/x, f32 LDS.
// ---------------------------------------------------------------------------
__global__ __launch_bounds__(256)
void scan_phase1(const __fp16* __restrict__ dth,
                 const float* __restrict__ xdbl,
                 const __fp16* __restrict__ xbh,
                 const float* __restrict__ A_log,
                 float* __restrict__ Pbuf, float* __restrict__ hbuf)
{
    int bx = blockIdx.x;
    int dg = bx & 31;
    int c  = (bx >> 5) & (NCHUNK - 1);
    int b  = bx >> 9;
    int d0 = dg * CHB;
    int t  = threadIdx.x;
    int s0 = (t & 3) * 4;
    int ch = t >> 2;
    int d  = d0 + ch;
    int l0 = c * LC;

    __shared__ __align__(16) float dt_t[LC][CHB];
    __shared__ __align__(16) float x_t[LC][CHB];
    __shared__ __align__(16) float B_t[LC][D_STATE];
    {
        int c4 = (t & 15) * 4;
        #pragma unroll
        for (int r = 0; r < 4; r++) {
            int row = (t >> 4) + r * 16;
            size_t g = (size_t)(b * SEQLEN + l0 + row) * D_INNER + d0 + c4;
            h4s_t d4 = *(const h4s_t*)(dth + g);
            h4s_t x4 = *(const h4s_t*)(xbh + g);
            float4 df = {(float)d4[0], (float)d4[1], (float)d4[2], (float)d4[3]};
            float4 xf = {(float)x4[0], (float)x4[1], (float)x4[2], (float)x4[3]};
            *(float4*)&dt_t[row][c4] = df;
            *(float4*)&x_t[row][c4]  = xf;
        }
        int brow = t >> 2, bc4 = (t & 3) * 4;
        *(float4*)&B_t[brow][bc4] =
            *(const float4*)(xdbl + (size_t)(b*SEQLEN + l0 + brow)*96 + DT_RANK + bc4);
    }
    float4 Al = *(const float4*)(A_log + d * D_STATE + s0);
    float As0 = -__expf(Al.x), As1 = -__expf(Al.y);
    float As2 = -__expf(Al.z), As3 = -__expf(Al.w);
    __syncthreads();

    float h0=0,h1=0,h2=0,h3=0, P0=1,P1=1,P2=1,P3=1;
    #pragma unroll 4
    for (int l = 0; l < LC; l++) {
        float dtv = dt_t[l][ch];
        float dx  = dtv * x_t[l][ch];
        float4 Bv = *(float4*)&B_t[l][s0];
        float a0 = __expf(dtv*As0), a1 = __expf(dtv*As1);
        float a2 = __expf(dtv*As2), a3 = __expf(dtv*As3);
        h0 = a0*h0 + dx*Bv.x;  P0 *= a0;
        h1 = a1*h1 + dx*Bv.y;  P1 *= a1;
        h2 = a2*h2 + dx*Bv.z;  P2 *= a2;
        h3 = a3*h3 + dx*Bv.w;  P3 *= a3;
    }
    size_t idx = (((size_t)(b * NCHUNK + c)) * D_INNER + d) * D_STATE + s0;
    float4 Pv = {P0,P1,P2,P3}, hv = {h0,h1,h2,h3};
    *(float4*)&Pbuf[idx] = Pv;
    *(float4*)&hbuf[idx] = hv;
}

__global__ __launch_bounds__(256)
void scan_carry(float* __restrict__ Pbuf, const float* __restrict__ hbuf)
{
    int t = blockIdx.x * 256 + threadIdx.x;
    int s0 = (t & 3) * 4;
    int bd = t >> 2;
    int d = bd & (D_INNER - 1);
    int b = bd >> 11;
    float4 h = {0,0,0,0};
    #pragma unroll
    for (int c = 0; c < NCHUNK; c++) {
        size_t idx = (((size_t)(b * NCHUNK + c)) * D_INNER + d) * D_STATE + s0;
        float4 Pc = *(float4*)&Pbuf[idx];
        float4 hl = *(const float4*)&hbuf[idx];
        *(float4*)&Pbuf[idx] = h;
        h.x = Pc.x*h.x + hl.x;  h.y = Pc.y*h.y + hl.y;
        h.z = Pc.z*h.z + hl.z;  h.w = Pc.w*h.w + hl.w;
    }
}

__global__ __launch_bounds__(256)
void scan_phase2(const __fp16* __restrict__ dth,
                 const float* __restrict__ xdbl,
                 const __fp16* __restrict__ xbh,
                 const float* __restrict__ A_log,
                 const float* __restrict__ Dvec,
                 const float* __restrict__ hinbuf,
                 const __fp16* __restrict__ zh,
                 __fp16* __restrict__ yh)
{
    int bx = blockIdx.x;
    int dg = bx & 31;
    int c  = (bx >> 5) & (NCHUNK - 1);
    int b  = bx >> 9;
    int d0 = dg * CHB;
    int t  = threadIdx.x;
    int s0 = (t & 3) * 4;
    int ch = t >> 2;
    int d  = d0 + ch;
    int l0 = c * LC;

    __shared__ __align__(16) float dt_t[LC][CHB];
    __shared__ __align__(16) float x_t[LC][CHB];
    __shared__ __align__(16) float B_t[LC][D_STATE];
    __shared__ __align__(16) float C_t[LC][D_STATE];
    __shared__ __align__(16) float y_t[LC][CHB];
    {
        int c4 = (t & 15) * 4;
        #pragma unroll
        for (int r = 0; r < 4; r++) {
            int row = (t >> 4) + r * 16;
            size_t g = (size_t)(b * SEQLEN + l0 + row) * D_INNER + d0 + c4;
            h4s_t d4 = *(const h4s_t*)(dth + g);
            h4s_t x4 = *(const h4s_t*)(xbh + g);
            float4 df = {(float)d4[0], (float)d4[1], (float)d4[2], (float)d4[3]};
            float4 xf = {(float)x4[0], (float)x4[1], (float)x4[2], (float)x4[3]};
            *(float4*)&dt_t[row][c4] = df;
            *(float4*)&x_t[row][c4]  = xf;
        }
        int brow = t >> 2, bc4 = (t & 3) * 4;
        const float* bcbase = xdbl + (size_t)(b*SEQLEN + l0 + brow)*96 + DT_RANK + bc4;
        *(float4*)&B_t[brow][bc4] = *(const float4*)bcbase;
        *(float4*)&C_t[brow][bc4] = *(const float4*)(bcbase + D_STATE);
    }
    float4 Al = *(const float4*)(A_log + d * D_STATE + s0);
    float As0 = -__expf(Al.x), As1 = -__expf(Al.y);
    float As2 = -__expf(Al.z), As3 = -__expf(Al.w);
    float Dd = Dvec[d];
    size_t idx = (((size_t)(b * NCHUNK + c)) * D_INNER + d) * D_STATE + s0;
    float4 hv = *(const float4*)&hinbuf[idx];
    float h0 = hv.x, h1 = hv.y, h2 = hv.z, h3 = hv.w;
    __syncthreads();

    #pragma unroll 4
    for (int l = 0; l < LC; l++) {
        float dtv = dt_t[l][ch];
        float xv  = x_t[l][ch];
        float dx  = dtv * xv;
        float4 Bv = *(float4*)&B_t[l][s0];
        float4 Cv = *(float4*)&C_t[l][s0];
        float a0 = __expf(dtv*As0), a1 = __expf(dtv*As1);
        float a2 = __expf(dtv*As2), a3 = __expf(dtv*As3);
        h0 = a0*h0 + dx*Bv.x;
        h1 = a1*h1 + dx*Bv.y;
        h2 = a2*h2 + dx*Bv.z;
        h3 = a3*h3 + dx*Bv.w;
        float p = h0*Cv.x + h1*Cv.y + h2*Cv.z + h3*Cv.w;
        p += __shfl_xor(p, 1);
        p += __shfl_xor(p, 2);
        if ((t & 3) == 0) y_t[l][ch] = p + xv * Dd;
    }
    __syncthreads();
    {
        int c4 = (t & 15) * 4;
        #pragma unroll
        for (int r = 0; r < 4; r++) {
            int row = (t >> 4) + r * 16;
            size_t g = (size_t)(b * SEQLEN + l0 + row) * D_INNER + d0 + c4;
            float4 y4 = *(float4*)&y_t[row][c4];
            h4s_t z4 = *(const h4s_t*)(zh + g);
            h4s_t o;
            o[0] = (__fp16)(y4.x * (float)z4[0]);
            o[1] = (__fp16)(y4.y * (float)z4[1]);
            o[2] = (__fp16)(y4.z * (float)z4[2]);
            o[3] = (__fp16)(y4.w * (float)z4[3]);
            *(h4s_t*)(yh + g) = o;
        }
    }
}

// ---------------------------------------------------------------------------
extern "C" void kernel_launch(void* const* d_in, const int* in_sizes, int n_in,
                              void* d_out, int out_size, void* d_ws, size_t ws_size,
                              hipStream_t stream)
{
    const float* x          = (const float*)d_in[0];
    const float* in_proj_w  = (const float*)d_in[1];
    const float* in_proj_b  = (const float*)d_in[2];
    const float* conv_w     = (const float*)d_in[3];
    const float* conv_b     = (const float*)d_in[4];
    const float* x_proj_w   = (const float*)d_in[5];
    const float* dt_proj_w  = (const float*)d_in[6];
    const float* dt_proj_b  = (const float*)d_in[7];
    const float* A_log      = (const float*)d_in[8];
    const float* Dv         = (const float*)d_in[9];
    const float* out_proj_w = (const float*)d_in[10];
    const float* out_proj_b = (const float*)d_in[11];
    float* out = (float*)d_out;

    // ws ≈ 268 MB confirmed (fill poison WRITE_SIZE) — no aliasing needed.
    char* base = (char*)d_ws;
    float*  xpre  = (float*) (base + 0);                    // 16.78 MB
    __fp16* zh    = (__fp16*)(base + 16777216);             //  8.39 MB
    __fp16* yh    = (__fp16*)(base + 25165824);             //  8.39 MB
    __fp16* xbh   = (__fp16*)(base + 33554432);             //  8.39 MB
    __fp16* xh    = (__fp16*)(base + 41943040);             //  4.19 MB
    __fp16* wh1   = (__fp16*)(base + 46137344);             //  8.39 MB
    __fp16* wh2   = (__fp16*)(base + 54525952);             //  4.19 MB
    __fp16* xpwh  = (__fp16*)(base + 58720256);             //  0.39 MB
    __fp16* dtwh  = (__fp16*)(base + 59113472);             //  0.26 MB
    float*  xdbl  = (float*) (base + 59375616);             //  0.79 MB
    __fp16* dtrh  = (__fp16*)(base + 60162048);             //  0.26 MB
    __fp16* dth   = (__fp16*)(base + 60424192);             //  8.39 MB
    float*  xpart = (float*) (base + 68812800);             // 12.58 MB
    float*  Pbuf  = (float*) (base + 81395712);             //  4.19 MB
    float*  hbuf  = (float*) (base + 85590016);             //  4.19 MB

    // 0) all f32->f16 conversions in one pass
    cvt_all<<<(NCVT + 255) / 256, 256, 0, stream>>>(
        x, in_proj_w, out_proj_w, x_proj_w, dt_proj_w,
        xh, wh1, wh2, xpwh, dtwh);

    // 1) in_proj (f16 MFMA + gll): xpre f32 / zh f16 silu
    {
        dim3 grid((2*D_INNER)/128, M_TOTAL/128, 1);
        gemm_gll<0,1><<<grid, 256, 0, stream>>>(
            xh, D_MODEL, wh1, D_MODEL, in_proj_b,
            xpre, zh, 2*D_INNER, D_MODEL);
    }
    // 2) causal depthwise conv + silu -> xbh f16
    conv_silu_kernel<<<(BATCH*SEQLEN*D_INNER)/256, 256, 0, stream>>>(
        xpre, conv_w, conv_b, xbh);
    // 3) x_proj (split-K f16 MFMA, gll): xdbl f32 + dtr_h f16
    {
        dim3 grid(M_TOTAL/64, XKSPLIT);
        xproj_gll<<<grid, 256, 0, stream>>>(xbh, xpwh, xpart);
        xproj_reduce<<<(M_TOTAL*96)/256, 256, 0, stream>>>(xpart, xdbl, dtrh);
    }
    // 4) dt_proj (f16 MFMA, K=64): dth = softplus(dtr @ dtw^T + b) f16
    {
        dim3 grid(D_INNER/128, M_TOTAL/128);
        dtproj_mfma<<<grid, 256, 0, stream>>>(dtrh, dtwh, dt_proj_b, dth);
    }
    // 5) chunked selective scan (+D skip, +z gate) -> yh f16
    {
        int nblk = BATCH * NCHUNK * (D_INNER / CHB);   // 1024
        scan_phase1<<<nblk, 256, 0, stream>>>(dth, xdbl, xbh, A_log, Pbuf, hbuf);
        scan_carry<<<(BATCH*D_INNER*4)/256, 256, 0, stream>>>(Pbuf, hbuf);
        scan_phase2<<<nblk, 256, 0, stream>>>(dth, xdbl, xbh, A_log, Dv, Pbuf, zh, yh);
    }
    // 6) out_proj: init out=bias, split-K atomic f16 MFMA
    out_init<<<(M_TOTAL*D_MODEL/4)/256, 256, 0, stream>>>(out, out_proj_b);
    {
        dim3 grid(D_MODEL/128, M_TOTAL/128, OSPLIT);
        gemm_gll<1,OSPLIT><<<grid, 256, 0, stream>>>(
            yh, D_INNER, wh2, D_INNER, nullptr,
            out, nullptr, D_MODEL, D_INNER);
    }
}

// Round 10
// 260.492 us; speedup vs baseline: 5.4922x; 1.0139x over previous
//
#include <hip/hip_runtime.h>
#include <math.h>

#define D_STATE 16
#define D_CONV 4
#define DT_RANK 64
#define D_INNER 2048
#define D_MODEL 1024
#define BATCH 2
#define SEQLEN 1024
#define M_TOTAL (BATCH*SEQLEN)  // 2048
#define REG ((size_t)M_TOTAL*D_INNER)

#define LC 64                    // scan chunk length
#define NCHUNK (SEQLEN/LC)       // 16
#define CHB 64                   // channels per scan block (4 s-lanes each)

#define XKSPLIT 16
#define XKCHUNK (D_INNER/XKSPLIT)   // 128
#define OSPLIT 4                 // out_proj split-K

typedef __fp16   h2s_t  __attribute__((ext_vector_type(2)));
typedef __fp16   h4s_t  __attribute__((ext_vector_type(4)));
typedef __fp16   h8s_t  __attribute__((ext_vector_type(8)));
typedef _Float16 half8  __attribute__((ext_vector_type(8)));  // MFMA operand
typedef float    floatx4 __attribute__((ext_vector_type(4)));

union HalfPack { h2s_t h2[4]; h8s_t h8; };

__device__ __forceinline__ float silu_f(float x) {
    return x / (1.0f + __expf(-x));
}
__device__ __forceinline__ float softplus_f(float x) {
    return fmaxf(x, 0.0f) + log1pf(__expf(-fabsf(x)));
}
__device__ __forceinline__ h8s_t pack8(const float4& v0, const float4& v1) {
    HalfPack p;
    p.h2[0] = __builtin_amdgcn_cvt_pkrtz(v0.x, v0.y);
    p.h2[1] = __builtin_amdgcn_cvt_pkrtz(v0.z, v0.w);
    p.h2[2] = __builtin_amdgcn_cvt_pkrtz(v1.x, v1.y);
    p.h2[3] = __builtin_amdgcn_cvt_pkrtz(v1.z, v1.w);
    return p.h8;
}
// async global->LDS, 16B per lane; LDS dst must be wave base + lane*16
__device__ __forceinline__ void gll16(const __fp16* g, __fp16* l) {
    __builtin_amdgcn_global_load_lds(
        (__attribute__((address_space(1))) const void*)g,
        (__attribute__((address_space(3))) void*)l, 16, 0, 0);
}

// ---------------------------------------------------------------------------
// One-shot f32->f16 conversion of x + all GEMM weights (segmented flat index).
// ---------------------------------------------------------------------------
#define N0 ((size_t)M_TOTAL*D_MODEL/8)       // x
#define N1 ((size_t)2*D_INNER*D_MODEL/8)     // in_proj_w
#define N2 ((size_t)D_MODEL*D_INNER/8)       // out_proj_w
#define N3 ((size_t)96*D_INNER/8)            // x_proj_w
#define N4 ((size_t)D_INNER*DT_RANK/8)       // dt_proj_w
#define NCVT (N0+N1+N2+N3+N4)

__global__ __launch_bounds__(256)
void cvt_all(const float* __restrict__ x,  const float* __restrict__ w1,
             const float* __restrict__ w2, const float* __restrict__ xpw,
             const float* __restrict__ dtw,
             __fp16* __restrict__ xh,  __fp16* __restrict__ wh1,
             __fp16* __restrict__ wh2, __fp16* __restrict__ xpwh,
             __fp16* __restrict__ dtwh)
{
    size_t i = (size_t)blockIdx.x * 256 + threadIdx.x;
    if (i >= NCVT) return;
    const float* src; __fp16* dst; size_t off;
    if      (i < N0)          { src = x;   dst = xh;   off = i; }
    else if (i < N0+N1)       { src = w1;  dst = wh1;  off = i - N0; }
    else if (i < N0+N1+N2)    { src = w2;  dst = wh2;  off = i - N0 - N1; }
    else if (i < N0+N1+N2+N3) { src = xpw; dst = xpwh; off = i - N0 - N1 - N2; }
    else                      { src = dtw; dst = dtwh; off = i - N0 - N1 - N2 - N3; }
    const float* p = src + off * 8;
    *(h8s_t*)(dst + off * 8) = pack8(*(const float4*)p, *(const float4*)(p + 4));
}

// out[m*D_MODEL+n] = bias[n]
__global__ __launch_bounds__(256)
void out_init(float* __restrict__ out, const float* __restrict__ bias)
{
    size_t i = (size_t)blockIdx.x * 256 + threadIdx.x;
    int col = (int)((i * 4) & (D_MODEL - 1));
    *(float4*)(out + i * 4) = *(const float4*)(bias + col);
}

// ---------------------------------------------------------------------------
// f16-input MFMA NT GEMM, gll staging, tile 128Mx64Nx32K.
// 4 waves; wave = 32x64 (2x4 MFMA tiles).  3 gll16/thread/iter, LDS 12 KB.
// MODE 0 (in_proj): v=acc+bias[n]; n<D_INNER -> out0 f32; else out1=f16 silu(v)
// MODE 1 (out_proj split-K): atomicAdd(out0[m*N+n], acc)  (bias pre-applied)
// ---------------------------------------------------------------------------
template<int MODE, int SPLITK>
__global__ __launch_bounds__(256)
void gemm_gll(const __fp16* __restrict__ A, int lda,
              const __fp16* __restrict__ B, int ldb,
              const float* __restrict__ bias,
              float* __restrict__ out0, __fp16* __restrict__ out1,
              int N, int K)
{
    constexpr int BM = 128, BN = 64, BK = 32;   // BK in halfs (64 B rows)
    __shared__ __align__(16) __fp16 As[BM * BK];
    __shared__ __align__(16) __fp16 Bs[BN * BK];

    const int tid  = threadIdx.x;
    const int bm   = blockIdx.y * BM;
    const int bn   = blockIdx.x * BN;
    const int wave = tid >> 6;
    const int lane = tid & 63;
    const int wm   = wave * 32;          // wave m-offset (4 waves x 32 = 128)
    const int fr   = lane & 15;
    const int fkh  = (lane >> 4) * 8;

    const int sr = tid >> 2;             // staging row 0..63
    const int sc = (tid & 3) * 8;        // staging col (halfs)

    const int kspan = K / SPLITK;
    const int k0    = (SPLITK > 1) ? blockIdx.z * kspan : 0;

    const __fp16* gA0 = A + (size_t)(bm + sr) * lda + k0 + sc;
    const __fp16* gA1 = A + (size_t)(bm + sr + 64) * lda + k0 + sc;
    const __fp16* gB0 = B + (size_t)(bn + sr) * ldb + k0 + sc;
    __fp16* lA0 = &As[sr * BK + sc];
    __fp16* lA1 = &As[(sr + 64) * BK + sc];
    __fp16* lB0 = &Bs[sr * BK + sc];

    floatx4 zero = {0.f, 0.f, 0.f, 0.f};
    floatx4 acc[2][4];
    #pragma unroll
    for (int i = 0; i < 2; i++)
        #pragma unroll
        for (int j = 0; j < 4; j++) acc[i][j] = zero;

    for (int kt = 0; kt < kspan; kt += BK) {
        gll16(gA0 + kt, lA0);
        gll16(gA1 + kt, lA1);
        gll16(gB0 + kt, lB0);
        __syncthreads();

        half8 af[2], bf[4];
        #pragma unroll
        for (int i = 0; i < 2; i++)
            af[i] = *(half8*)&As[(wm + i*16 + fr) * BK + fkh];
        #pragma unroll
        for (int j = 0; j < 4; j++)
            bf[j] = *(half8*)&Bs[(j*16 + fr) * BK + fkh];
        #pragma unroll
        for (int i = 0; i < 2; i++)
            #pragma unroll
            for (int j = 0; j < 4; j++)
                acc[i][j] = __builtin_amdgcn_mfma_f32_16x16x32_f16(
                    af[i], bf[j], acc[i][j], 0, 0, 0);
        __syncthreads();
    }

    // epilogue: C/D layout col=lane&15, row=(lane>>4)*4+reg
    const int rbase = (lane >> 4) * 4;
    #pragma unroll
    for (int i = 0; i < 2; i++) {
        #pragma unroll
        for (int j = 0; j < 4; j++) {
            int n = bn + j*16 + fr;
            float bv = (MODE == 0) ? bias[n] : 0.0f;
            #pragma unroll
            for (int r = 0; r < 4; r++) {
                int m = bm + wm + i*16 + rbase + r;
                float v = acc[i][j][r] + bv;
                if (MODE == 0) {
                    if (n < D_INNER) out0[(size_t)m * D_INNER + n] = v;
                    else out1[(size_t)m * D_INNER + (n - D_INNER)] = (__fp16)silu_f(v);
                } else {
                    atomicAdd(out0 + (size_t)m * N + n, v);
                }
            }
        }
    }
}

// ---------------------------------------------------------------------------
// x_proj split-K, gll staging from f16: partials[p][m][96].
// ---------------------------------------------------------------------------
__global__ __launch_bounds__(256)
void xproj_gll(const __fp16* __restrict__ A,      // xbh, lda = D_INNER
               const __fp16* __restrict__ B,      // xpwh (96 x D_INNER)
               float* __restrict__ partials)
{
    __shared__ __align__(16) __fp16 As[64 * 32];
    __shared__ __align__(16) __fp16 Bs[96 * 32];

    const int tid = threadIdx.x;
    const int mt  = blockIdx.x * 64;
    const int p   = blockIdx.y;
    const int k0  = p * XKCHUNK;
    const int wave = tid >> 6;
    const int lane = tid & 63;
    const int fr = lane & 15;
    const int fkh = (lane >> 4) * 8;

    floatx4 zero = {0.f, 0.f, 0.f, 0.f};
    floatx4 acc[6];
    #pragma unroll
    for (int j = 0; j < 6; j++) acc[j] = zero;

    for (int kt = 0; kt < XKCHUNK; kt += 32) {
        {
            int row = tid >> 2, col = (tid & 3) * 8;
            gll16(A + (size_t)(mt + row) * D_INNER + k0 + kt + col, &As[tid * 8]);
            gll16(B + (size_t)row * D_INNER + k0 + kt + col, &Bs[tid * 8]);
            if (tid < 128) {
                int c = tid + 256;
                gll16(B + (size_t)(c >> 2) * D_INNER + k0 + kt + (c & 3) * 8,
                      &Bs[c * 8]);
            }
        }
        __syncthreads();

        half8 af = *(half8*)&As[(wave * 16 + fr) * 32 + fkh];
        #pragma unroll
        for (int j = 0; j < 6; j++) {
            half8 bf = *(half8*)&Bs[(j * 16 + fr) * 32 + fkh];
            acc[j] = __builtin_amdgcn_mfma_f32_16x16x32_f16(af, bf, acc[j], 0, 0, 0);
        }
        __syncthreads();
    }

    const int rbase = (lane >> 4) * 4;
    float* outp = partials + ((size_t)p * M_TOTAL + mt + wave * 16) * 96;
    #pragma unroll
    for (int j = 0; j < 6; j++) {
        int n = j * 16 + fr;
        #pragma unroll
        for (int r = 0; r < 4; r++)
            outp[(size_t)(rbase + r) * 96 + n] = acc[j][r];
    }
}

// reduce partials -> xdbl f32 (all 96) + dtr_h f16 (first 64 cols)
__global__ __launch_bounds__(256)
void xproj_reduce(const float* __restrict__ partials,
                  float* __restrict__ xdbl, __fp16* __restrict__ dtrh)
{
    int i = blockIdx.x * 256 + threadIdx.x;
    float s = 0.0f;
    #pragma unroll
    for (int p = 0; p < XKSPLIT; p++)
        s += partials[(size_t)p * M_TOTAL * 96 + i];
    xdbl[i] = s;
    int col = i % 96;
    if (col < DT_RANK) dtrh[(size_t)(i / 96) * DT_RANK + col] = (__fp16)s;
}

// ---------------------------------------------------------------------------
// dt_proj f16 MFMA: dt = softplus(dtr @ dtw^T + b), K=64, output f16.
// ---------------------------------------------------------------------------
__global__ __launch_bounds__(256)
void dtproj_mfma(const __fp16* __restrict__ A,    // dtr_h (M x 64)
                 const __fp16* __restrict__ B,    // dtwh (D_INNER x 64)
                 const float* __restrict__ bias,
                 __fp16* __restrict__ dth)
{
    __shared__ __align__(16) __fp16 As[128 * 64];
    __shared__ __align__(16) __fp16 Bs[128 * 64];

    const int tid  = threadIdx.x;
    const int bm   = blockIdx.y * 128;
    const int bn   = blockIdx.x * 128;
    const int wave = tid >> 6;
    const int lane = tid & 63;
    const int wm   = (wave >> 1) * 64;
    const int wn   = (wave & 1) * 64;
    const int fr   = lane & 15;
    const int fkh  = (lane >> 4) * 8;

    #pragma unroll
    for (int r = 0; r < 4; r++) {
        int c = tid + 256 * r;
        int row = c >> 3, col = (c & 7) * 8;
        gll16(A + (size_t)(bm + row) * DT_RANK + col, &As[c * 8]);
        gll16(B + (size_t)(bn + row) * DT_RANK + col, &Bs[c * 8]);
    }
    __syncthreads();

    floatx4 zero = {0.f, 0.f, 0.f, 0.f};
    floatx4 acc[4][4];
    #pragma unroll
    for (int i = 0; i < 4; i++)
        #pragma unroll
        for (int j = 0; j < 4; j++) acc[i][j] = zero;

    #pragma unroll
    for (int ks = 0; ks < 64; ks += 32) {
        half8 af[4], bf[4];
        #pragma unroll
        for (int i = 0; i < 4; i++)
            af[i] = *(half8*)&As[(wm + i*16 + fr) * 64 + ks + fkh];
        #pragma unroll
        for (int j = 0; j < 4; j++)
            bf[j] = *(half8*)&Bs[(wn + j*16 + fr) * 64 + ks + fkh];
        #pragma unroll
        for (int i = 0; i < 4; i++)
            #pragma unroll
            for (int j = 0; j < 4; j++)
                acc[i][j] = __builtin_amdgcn_mfma_f32_16x16x32_f16(
                    af[i], bf[j], acc[i][j], 0, 0, 0);
    }

    const int rbase = (lane >> 4) * 4;
    #pragma unroll
    for (int i = 0; i < 4; i++) {
        #pragma unroll
        for (int j = 0; j < 4; j++) {
            int n = bn + wn + j*16 + fr;
            float bv = bias[n];
            #pragma unroll
            for (int r = 0; r < 4; r++) {
                int m = bm + wm + i*16 + rbase + r;
                dth[(size_t)m * D_INNER + n] = (__fp16)softplus_f(acc[i][j][r] + bv);
            }
        }
    }
}

// ---------------------------------------------------------------------------
// Causal depthwise conv (4 taps, left pad 3) + SiLU -> f16.  Layout (b,l,c).
// ---------------------------------------------------------------------------
__global__ __launch_bounds__(256)
void conv_silu_kernel(const float* __restrict__ xpre,
                      const float* __restrict__ conv_w,
                      const float* __restrict__ conv_b,
                      __fp16* __restrict__ xbh)
{
    int idx = blockIdx.x * blockDim.x + threadIdx.x;
    int c = idx % D_INNER;
    int l = (idx / D_INNER) % SEQLEN;
    int b = idx / (D_INNER * SEQLEN);
    const float* base = xpre + (size_t)b * SEQLEN * D_INNER + c;
    float w0 = conv_w[c*4+0], w1 = conv_w[c*4+1];
    float w2 = conv_w[c*4+2], w3 = conv_w[c*4+3];
    float acc = conv_b[c];
    if (l >= 3) acc += w0 * base[(l-3) * D_INNER];
    if (l >= 2) acc += w1 * base[(l-2) * D_INNER];
    if (l >= 1) acc += w2 * base[(l-1) * D_INNER];
    acc += w3 * base[l * D_INNER];
    xbh[idx] = (__fp16)silu_f(acc);
}

// ---------------------------------------------------------------------------
// Chunked selective scan, state-quad threads; f16 global dt/x, f32 LDS.
// ---------------------------------------------------------------------------
__global__ __launch_bounds__(256)
void scan_phase1(const __fp16* __restrict__ dth,
                 const float* __restrict__ xdbl,
                 const __fp16* __restrict__ xbh,
                 const float* __restrict__ A_log,
                 float* __restrict__ Pbuf, float* __restrict__ hbuf)
{
    int bx = blockIdx.x;
    int dg = bx & 31;
    int c  = (bx >> 5) & (NCHUNK - 1);
    int b  = bx >> 9;
    int d0 = dg * CHB;
    int t  = threadIdx.x;
    int s0 = (t & 3) * 4;
    int ch = t >> 2;
    int d  = d0 + ch;
    int l0 = c * LC;

    __shared__ __align__(16) float dt_t[LC][CHB];
    __shared__ __align__(16) float x_t[LC][CHB];
    __shared__ __align__(16) float B_t[LC][D_STATE];
    {
        int c4 = (t & 15) * 4;
        #pragma unroll
        for (int r = 0; r < 4; r++) {
            int row = (t >> 4) + r * 16;
            size_t g = (size_t)(b * SEQLEN + l0 + row) * D_INNER + d0 + c4;
            h4s_t d4 = *(const h4s_t*)(dth + g);
            h4s_t x4 = *(const h4s_t*)(xbh + g);
            float4 df = {(float)d4[0], (float)d4[1], (float)d4[2], (float)d4[3]};
            float4 xf = {(float)x4[0], (float)x4[1], (float)x4[2], (float)x4[3]};
            *(float4*)&dt_t[row][c4] = df;
            *(float4*)&x_t[row][c4]  = xf;
        }
        int brow = t >> 2, bc4 = (t & 3) * 4;
        *(float4*)&B_t[brow][bc4] =
            *(const float4*)(xdbl + (size_t)(b*SEQLEN + l0 + brow)*96 + DT_RANK + bc4);
    }
    float4 Al = *(const float4*)(A_log + d * D_STATE + s0);
    float As0 = -__expf(Al.x), As1 = -__expf(Al.y);
    float As2 = -__expf(Al.z), As3 = -__expf(Al.w);
    __syncthreads();

    float h0=0,h1=0,h2=0,h3=0, P0=1,P1=1,P2=1,P3=1;
    #pragma unroll 4
    for (int l = 0; l < LC; l++) {
        float dtv = dt_t[l][ch];
        float dx  = dtv * x_t[l][ch];
        float4 Bv = *(float4*)&B_t[l][s0];
        float a0 = __expf(dtv*As0), a1 = __expf(dtv*As1);
        float a2 = __expf(dtv*As2), a3 = __expf(dtv*As3);
        h0 = a0*h0 + dx*Bv.x;  P0 *= a0;
        h1 = a1*h1 + dx*Bv.y;  P1 *= a1;
        h2 = a2*h2 + dx*Bv.z;  P2 *= a2;
        h3 = a3*h3 + dx*Bv.w;  P3 *= a3;
    }
    size_t idx = (((size_t)(b * NCHUNK + c)) * D_INNER + d) * D_STATE + s0;
    float4 Pv = {P0,P1,P2,P3}, hv = {h0,h1,h2,h3};
    *(float4*)&Pbuf[idx] = Pv;
    *(float4*)&hbuf[idx] = hv;
}

__global__ __launch_bounds__(256)
void scan_carry(float* __restrict__ Pbuf, const float* __restrict__ hbuf)
{
    int t = blockIdx.x * 256 + threadIdx.x;
    int s0 = (t & 3) * 4;
    int bd = t >> 2;
    int d = bd & (D_INNER - 1);
    int b = bd >> 11;
    float4 h = {0,0,0,0};
    #pragma unroll
    for (int c = 0; c < NCHUNK; c++) {
        size_t idx = (((size_t)(b * NCHUNK + c)) * D_INNER + d) * D_STATE + s0;
        float4 Pc = *(float4*)&Pbuf[idx];
        float4 hl = *(const float4*)&hbuf[idx];
        *(float4*)&Pbuf[idx] = h;
        h.x = Pc.x*h.x + hl.x;  h.y = Pc.y*h.y + hl.y;
        h.z = Pc.z*h.z + hl.z;  h.w = Pc.w*h.w + hl.w;
    }
}

__global__ __launch_bounds__(256)
void scan_phase2(const __fp16* __restrict__ dth,
                 const float* __restrict__ xdbl,
                 const __fp16* __restrict__ xbh,
                 const float* __restrict__ A_log,
                 const float* __restrict__ Dvec,
                 const float* __restrict__ hinbuf,
                 const __fp16* __restrict__ zh,
                 __fp16* __restrict__ yh)
{
    int bx = blockIdx.x;
    int dg = bx & 31;
    int c  = (bx >> 5) & (NCHUNK - 1);
    int b  = bx >> 9;
    int d0 = dg * CHB;
    int t  = threadIdx.x;
    int s0 = (t & 3) * 4;
    int ch = t >> 2;
    int d  = d0 + ch;
    int l0 = c * LC;

    __shared__ __align__(16) float dt_t[LC][CHB];
    __shared__ __align__(16) float x_t[LC][CHB];
    __shared__ __align__(16) float B_t[LC][D_STATE];
    __shared__ __align__(16) float C_t[LC][D_STATE];
    __shared__ __align__(16) float y_t[LC][CHB];
    {
        int c4 = (t & 15) * 4;
        #pragma unroll
        for (int r = 0; r < 4; r++) {
            int row = (t >> 4) + r * 16;
            size_t g = (size_t)(b * SEQLEN + l0 + row) * D_INNER + d0 + c4;
            h4s_t d4 = *(const h4s_t*)(dth + g);
            h4s_t x4 = *(const h4s_t*)(xbh + g);
            float4 df = {(float)d4[0], (float)d4[1], (float)d4[2], (float)d4[3]};
            float4 xf = {(float)x4[0], (float)x4[1], (float)x4[2], (float)x4[3]};
            *(float4*)&dt_t[row][c4] = df;
            *(float4*)&x_t[row][c4]  = xf;
        }
        int brow = t >> 2, bc4 = (t & 3) * 4;
        const float* bcbase = xdbl + (size_t)(b*SEQLEN + l0 + brow)*96 + DT_RANK + bc4;
        *(float4*)&B_t[brow][bc4] = *(const float4*)bcbase;
        *(float4*)&C_t[brow][bc4] = *(const float4*)(bcbase + D_STATE);
    }
    float4 Al = *(const float4*)(A_log + d * D_STATE + s0);
    float As0 = -__expf(Al.x), As1 = -__expf(Al.y);
    float As2 = -__expf(Al.z), As3 = -__expf(Al.w);
    float Dd = Dvec[d];
    size_t idx = (((size_t)(b * NCHUNK + c)) * D_INNER + d) * D_STATE + s0;
    float4 hv = *(const float4*)&hinbuf[idx];
    float h0 = hv.x, h1 = hv.y, h2 = hv.z, h3 = hv.w;
    __syncthreads();

    #pragma unroll 4
    for (int l = 0; l < LC; l++) {
        float dtv = dt_t[l][ch];
        float xv  = x_t[l][ch];
        float dx  = dtv * xv;
        float4 Bv = *(float4*)&B_t[l][s0];
        float4 Cv = *(float4*)&C_t[l][s0];
        float a0 = __expf(dtv*As0), a1 = __expf(dtv*As1);
        float a2 = __expf(dtv*As2), a3 = __expf(dtv*As3);
        h0 = a0*h0 + dx*Bv.x;
        h1 = a1*h1 + dx*Bv.y;
        h2 = a2*h2 + dx*Bv.z;
        h3 = a3*h3 + dx*Bv.w;
        float p = h0*Cv.x + h1*Cv.y + h2*Cv.z + h3*Cv.w;
        p += __shfl_xor(p, 1);
        p += __shfl_xor(p, 2);
        if ((t & 3) == 0) y_t[l][ch] = p + xv * Dd;
    }
    __syncthreads();
    {
        int c4 = (t & 15) * 4;
        #pragma unroll
        for (int r = 0; r < 4; r++) {
            int row = (t >> 4) + r * 16;
            size_t g = (size_t)(b * SEQLEN + l0 + row) * D_INNER + d0 + c4;
            float4 y4 = *(float4*)&y_t[row][c4];
            h4s_t z4 = *(const h4s_t*)(zh + g);
            h4s_t o;
            o[0] = (__fp16)(y4.x * (float)z4[0]);
            o[1] = (__fp16)(y4.y * (float)z4[1]);
            o[2] = (__fp16)(y4.z * (float)z4[2]);
            o[3] = (__fp16)(y4.w * (float)z4[3]);
            *(h4s_t*)(yh + g) = o;
        }
    }
}

// ---------------------------------------------------------------------------
extern "C" void kernel_launch(void* const* d_in, const int* in_sizes, int n_in,
                              void* d_out, int out_size, void* d_ws, size_t ws_size,
                              hipStream_t stream)
{
    const float* x          = (const float*)d_in[0];
    const float* in_proj_w  = (const float*)d_in[1];
    const float* in_proj_b  = (const float*)d_in[2];
    const float* conv_w     = (const float*)d_in[3];
    const float* conv_b     = (const float*)d_in[4];
    const float* x_proj_w   = (const float*)d_in[5];
    const float* dt_proj_w  = (const float*)d_in[6];
    const float* dt_proj_b  = (const float*)d_in[7];
    const float* A_log      = (const float*)d_in[8];
    const float* Dv         = (const float*)d_in[9];
    const float* out_proj_w = (const float*)d_in[10];
    const float* out_proj_b = (const float*)d_in[11];
    float* out = (float*)d_out;

    char* base = (char*)d_ws;
    float*  xpre  = (float*) (base + 0);                    // 16.78 MB
    __fp16* zh    = (__fp16*)(base + 16777216);             //  8.39 MB
    __fp16* yh    = (__fp16*)(base + 25165824);             //  8.39 MB
    __fp16* xbh   = (__fp16*)(base + 33554432);             //  8.39 MB
    __fp16* xh    = (__fp16*)(base + 41943040);             //  4.19 MB
    __fp16* wh1   = (__fp16*)(base + 46137344);             //  8.39 MB
    __fp16* wh2   = (__fp16*)(base + 54525952);             //  4.19 MB
    __fp16* xpwh  = (__fp16*)(base + 58720256);             //  0.39 MB
    __fp16* dtwh  = (__fp16*)(base + 59113472);             //  0.26 MB
    float*  xdbl  = (float*) (base + 59375616);             //  0.79 MB
    __fp16* dtrh  = (__fp16*)(base + 60162048);             //  0.26 MB
    __fp16* dth   = (__fp16*)(base + 60424192);             //  8.39 MB
    float*  xpart = (float*) (base + 68812800);             // 12.58 MB
    float*  Pbuf  = (float*) (base + 81395712);             //  4.19 MB
    float*  hbuf  = (float*) (base + 85590016);             //  4.19 MB

    // 0) all f32->f16 conversions in one pass
    cvt_all<<<(NCVT + 255) / 256, 256, 0, stream>>>(
        x, in_proj_w, out_proj_w, x_proj_w, dt_proj_w,
        xh, wh1, wh2, xpwh, dtwh);

    // 1) in_proj (f16 MFMA + gll, 128x64 tiles -> 1024 blocks)
    {
        dim3 grid((2*D_INNER)/64, M_TOTAL/128, 1);
        gemm_gll<0,1><<<grid, 256, 0, stream>>>(
            xh, D_MODEL, wh1, D_MODEL, in_proj_b,
            xpre, zh, 2*D_INNER, D_MODEL);
    }
    // 2) causal depthwise conv + silu -> xbh f16
    conv_silu_kernel<<<(BATCH*SEQLEN*D_INNER)/256, 256, 0, stream>>>(
        xpre, conv_w, conv_b, xbh);
    // 3) x_proj (split-K f16 MFMA, gll): xdbl f32 + dtr_h f16
    {
        dim3 grid(M_TOTAL/64, XKSPLIT);
        xproj_gll<<<grid, 256, 0, stream>>>(xbh, xpwh, xpart);
        xproj_reduce<<<(M_TOTAL*96)/256, 256, 0, stream>>>(xpart, xdbl, dtrh);
    }
    // 4) dt_proj (f16 MFMA, K=64): dth = softplus(dtr @ dtw^T + b) f16
    {
        dim3 grid(D_INNER/128, M_TOTAL/128);
        dtproj_mfma<<<grid, 256, 0, stream>>>(dtrh, dtwh, dt_proj_b, dth);
    }
    // 5) chunked selective scan (+D skip, +z gate) -> yh f16
    {
        int nblk = BATCH * NCHUNK * (D_INNER / CHB);   // 1024
        scan_phase1<<<nblk, 256, 0, stream>>>(dth, xdbl, xbh, A_log, Pbuf, hbuf);
        scan_carry<<<(BATCH*D_INNER*4)/256, 256, 0, stream>>>(Pbuf, hbuf);
        scan_phase2<<<nblk, 256, 0, stream>>>(dth, xdbl, xbh, A_log, Dv, Pbuf, zh, yh);
    }
    // 6) out_proj: init out=bias, split-K atomic f16 MFMA (128x64 tiles)
    out_init<<<(M_TOTAL*D_MODEL/4)/256, 256, 0, stream>>>(out, out_proj_b);
    {
        dim3 grid(D_MODEL/64, M_TOTAL/128, OSPLIT);
        gemm_gll<1,OSPLIT><<<grid, 256, 0, stream>>>(
            yh, D_INNER, wh2, D_INNER, nullptr,
            out, nullptr, D_MODEL, D_INNER);
    }
}